// Round 3
// baseline (1642.382 us; speedup 1.0000x reference)
//
#include <hip/hip_runtime.h>
#include <hip/hip_bf16.h>

#define SLOTS 5
#define PER 15
#define EGO_DD 32
#define PAIR_DD 10
#define TER_DD 81
#define DX 198
#define ZDIM 332
#define NTOK (64*2048)
#define NEGB (-3.402823466e38f)
#define ST 36      // padded stride for [5][32] f32 slot arrays
#define HBST 68    // padded stride for [5][64] f32 ffn hidden
#define YHS 40     // padded stride (shorts) for bf16 [5][32]
#define HHS 72     // padded stride (shorts) for bf16 [5][64]

// ---- B-fragment tile table ----
#define T_EGO   0
#define T_PAIR  4
#define T_TER   6
#define T_INV   18
#define T_Q     20
#define T_K     22
#define T_V     24
#define T_O     26
#define T_W1    28
#define T_W2    32
#define T_APQ   36
#define T_APK   40
#define T_FLAT  42
#define T_VEGO  52
#define T_VH    56
#define T_ZW1   60
#define T_ZW2   148
#define T_TOT   180
#define WS_NEED (T_TOT*512*2)

// ---- per-wave LDS pool layout (floats), PW = 1540 ----
#define PW 1540
#define OF_EGO 0
#define OF_TV  64
#define OF_YB  244
#define OF_U   424
#define OF_AT  964
#define OF_ZB  1064
#define OF_QEB 1396
#define OF_EGH 1428
#define OF_RU  1460
#define OF_SM  1492

typedef float f32x4 __attribute__((ext_vector_type(4)));
typedef short s16x8 __attribute__((ext_vector_type(8)));
typedef short s16x4 __attribute__((ext_vector_type(4)));
#define MFMA(a,b,c) __builtin_amdgcn_mfma_f32_16x16x32_bf16(a,b,c,0,0,0)
// Intra-wave phase separator: compiler memory fence only (same-wave LDS is
// ordered in HW; cross-wave data only at the z-phase barriers).
#define WF() asm volatile("" ::: "memory")

struct P {
  const float *x,*w_ego,*b_ego,*w_pair,*b_pair,*w_ter,*b_ter,*w_invtok,*b_invtok,
    *ln1_s,*ln1_b,*wq,*bq,*wk,*bk,*wv,*bv,*wo,*bo,*ln2_s,*ln2_b,*w1,*b1,*w2,*b2,
    *sp_ln_s,*sp_ln_b,*sp_w,*sp_b,*sp_lt,*ap_wq,*ap_bq,*ap_wk,*ap_bk,*ap_we,*ap_be,
    *flat_w,*flat_b,*vr_wego,*vr_bego,*vr_ln_s,*vr_ln_b,*vr_wh,*vr_bh,*vr_wl,*vr_bl,
    *z_w1,*z_b1,*z_ln1_s,*z_ln1_b,*z_w2,*z_b2,*z_ln2_s,*z_ln2_b;
};

__device__ __forceinline__ short f2bf(float x){
  __hip_bfloat16 h = __float2bfloat16(x);
  return *reinterpret_cast<short*>(&h);
}
__device__ __forceinline__ float tanh_f(float x){
  float e = __expf(2.f*x);
  return 1.f - 2.f/(e+1.f);
}
__device__ __forceinline__ float gelu_f(float x){
  return 0.5f*x*(1.f+tanh_f(0.7978845608028654f*(x + 0.044715f*x*x*x)));
}
__device__ __forceinline__ s16x8 packrow(const float* r){
  s16x8 af;
  #pragma unroll
  for(int j=0;j<8;j++) af[j]=f2bf(r[j]);
  return af;
}
__device__ __forceinline__ s16x8 packrowb(const float* r, int k0, int K){
  s16x8 af;
  #pragma unroll
  for(int j=0;j<8;j++) af[j] = (k0+j<K) ? f2bf(r[k0+j]) : (short)0;
  return af;
}

// dual interleaved 32-lane reduce (two independent chains pipeline)
__device__ __forceinline__ void red5_2(float&a,float&b){
  a+=__shfl_xor(a,16,32); b+=__shfl_xor(b,16,32);
  a+=__shfl_xor(a,8,32);  b+=__shfl_xor(b,8,32);
  a+=__shfl_xor(a,4,32);  b+=__shfl_xor(b,4,32);
  a+=__shfl_xor(a,2,32);  b+=__shfl_xor(b,2,32);
  a+=__shfl_xor(a,1,32);  b+=__shfl_xor(b,1,32);
}
__device__ __forceinline__ float red5(float a){
  a+=__shfl_xor(a,16,32); a+=__shfl_xor(a,8,32); a+=__shfl_xor(a,4,32);
  a+=__shfl_xor(a,2,32);  a+=__shfl_xor(a,1,32);
  return a;
}

// LayerNorm (dual-tree) -> bf16 dst (stride YHS); sc/bi are lane's values at i=l&31
__device__ void ln5h(const float* src, short* dst, float sc, float bi, int l){
  for (int sp=0; sp<6; sp+=2){
    int sl = sp + (l>>5), i = l&31;
    bool act = sl < SLOTS;
    float v = act ? src[sl*ST+i] : 0.f;
    float s=v, ss=v*v;
    red5_2(s,ss);
    float mu=s*(1.f/32.f);
    float rstd=rsqrtf(ss*(1.f/32.f)-mu*mu+1e-6f);
    if(act) dst[sl*YHS+i]=f2bf((v-mu)*rstd*sc+bi);
  }
}
// fused sp+vr LN on the same src: vr -> bf16 ath, sp scores reduced -> scs
__device__ void ln5_spvr(const float* src, short* ath, float* scs,
    float s_sp,float b_sp,float s_vr,float b_vr,float w_sp,float spb,int l){
  for (int sp=0; sp<6; sp+=2){
    int sl = sp + (l>>5), i = l&31;
    bool act = sl < SLOTS;
    float v = act ? src[sl*ST+i] : 0.f;
    float s=v, ss=v*v;
    red5_2(s,ss);
    float mu=s*(1.f/32.f);
    float rstd=rsqrtf(ss*(1.f/32.f)-mu*mu+1e-6f);
    float d=(v-mu)*rstd;
    if(act) ath[sl*YHS+i]=f2bf(d*s_vr+b_vr);
    float t=(d*s_sp+b_sp)*w_sp;
    t=red5(t);
    if(act && i==0) scs[sl]=t+spb;
  }
}

// pack all weights into bf16 B-fragments
__global__ __launch_bounds__(256) void k_prep(P p, short* __restrict__ ws){
  int idx = blockIdx.x*256 + threadIdx.x;
  if (idx >= T_TOT*512) return;
  int j = idx & 7, lane = (idx>>3)&63, tile = idx>>9;
  const float* src; int K,N,ntc,t0;
  if      (tile < T_PAIR){ src=p.w_ego;   K=32;  N=64;  ntc=4; t0=T_EGO; }
  else if (tile < T_TER ){ src=p.w_pair;  K=10;  N=32;  ntc=2; t0=T_PAIR; }
  else if (tile < T_INV ){ src=p.w_ter;   K=81;  N=64;  ntc=4; t0=T_TER; }
  else if (tile < T_Q   ){ src=p.w_invtok;K=10;  N=32;  ntc=2; t0=T_INV; }
  else if (tile < T_K   ){ src=p.wq;      K=32;  N=32;  ntc=2; t0=T_Q; }
  else if (tile < T_V   ){ src=p.wk;      K=32;  N=32;  ntc=2; t0=T_K; }
  else if (tile < T_O   ){ src=p.wv;      K=32;  N=32;  ntc=2; t0=T_V; }
  else if (tile < T_W1  ){ src=p.wo;      K=32;  N=32;  ntc=2; t0=T_O; }
  else if (tile < T_W2  ){ src=p.w1;      K=32;  N=64;  ntc=4; t0=T_W1; }
  else if (tile < T_APQ ){ src=p.w2;      K=64;  N=32;  ntc=2; t0=T_W2; }
  else if (tile < T_APK ){ src=p.ap_wq;   K=64;  N=32;  ntc=2; t0=T_APQ; }
  else if (tile < T_FLAT){ src=p.ap_wk;   K=32;  N=32;  ntc=2; t0=T_APK; }
  else if (tile < T_VEGO){ src=p.flat_w;  K=160; N=32;  ntc=2; t0=T_FLAT; }
  else if (tile < T_VH  ){ src=p.vr_wego; K=64;  N=32;  ntc=2; t0=T_VEGO; }
  else if (tile < T_ZW1 ){ src=p.vr_wh;   K=64;  N=32;  ntc=2; t0=T_VH; }
  else if (tile < T_ZW2 ){ src=p.z_w1;    K=ZDIM;N=128; ntc=8; t0=T_ZW1; }
  else                   { src=p.z_w2;    K=128; N=128; ntc=8; t0=T_ZW2; }
  int tl = tile - t0, ktI = tl/ntc, ntI = tl%ntc;
  int k = ktI*32 + ((lane>>4)<<3) + j, n = ntI*16 + (lane&15);
  float v = (k<K && n<N) ? src[k*N+n] : 0.f;
  ws[idx] = f2bf(v);
}

#define WV 4
__global__ __launch_bounds__(256) void k_token(P p, float* __restrict__ outp,
                                               const short* __restrict__ wsb) {
  __shared__ __align__(16) float pool[WV*PW];
  __shared__ int mkA[WV][5];
  __shared__ int mksA[WV][5];
  const s16x8* wsv = (const s16x8*)wsb;
  int wid = threadIdx.x >> 6, l = threadIdx.x & 63;
  float* W   = pool + wid*PW;
  float* ego = W + OF_EGO;
  float* tv  = W + OF_TV;
  float* yb  = W + OF_YB;                 // f32 view (ap raw scores)
  short* ybh = (short*)(W + OF_YB);       // bf16 view (LN1/LN2/attn-y)
  float* U   = W + OF_U;
  float* at  = W + OF_AT;
  short* ath = (short*)(W + OF_AT);       // vr-LN bf16 (at region, post-attention)
  float* zb  = W + OF_ZB;
  float* qeb = W + OF_QEB;
  float* egh = W + OF_EGH;
  float* ru  = W + OF_RU;
  float* sm  = W + OF_SM;
  float* scs = sm+0; float* wts = sm+5; float* alp = sm+10; float* lg = sm+16;
  float* a2 = sm+26; float* aps = sm+36;
  int* mk  = mkA[wid];
  int* mks = mksA[wid];
  // U overlays
  float* xb = U;                // phase A
  float* qb = U;  float* kb = U+180;  float* vb = U+360;   // phase B
  float* hb = U;                                            // phase C (f32 raw)
  short* hbh = (short*)(U + 344);                            // phase C (bf16 gelu'd)
  float* vq = U;                // tail: vh raw output
  long tok = (long)blockIdx.x*WV + wid;
  int m = l & 15, q = l >> 4;
  int mm = m < 5 ? m : 4;
  int i5 = l & 31, l16 = l & 15;
#define BFR(tile) wsv[(tile)*64 + l]

  // ---- hoisted per-lane constants (live in VGPRs across all fences) ----
  float r_binv0=p.b_invtok[m],  r_binv1=p.b_invtok[16+m];
  float r_bq0=p.bq[m], r_bq1=p.bq[16+m];
  float r_bk0=p.bk[m], r_bk1=p.bk[16+m];
  float r_bv0=p.bv[m], r_bv1=p.bv[16+m];
  float r_bo0=p.bo[m], r_bo1=p.bo[16+m];
  float r_b10=p.b1[m], r_b11=p.b1[16+m], r_b12=p.b1[32+m], r_b13=p.b1[48+m];
  float r_b20=p.b2[m], r_b21=p.b2[16+m];
  float r_vbh0=p.vr_bh[m], r_vbh1=p.vr_bh[16+m];
  float r_bego0=p.b_ego[l16], r_bego1=p.b_ego[16+l16],
        r_bego2=p.b_ego[32+l16], r_bego3=p.b_ego[48+l16];
  float r_bpair0=p.b_pair[l16], r_bpair1=p.b_pair[16+l16];
  float r_bter0=p.b_ter[l16], r_bter1=p.b_ter[16+l16],
        r_bter2=p.b_ter[32+l16], r_bter3=p.b_ter[48+l16];
  float r_apbq0=p.ap_bq[l16], r_apbq1=p.ap_bq[16+l16];
  float r_fb0=p.flat_b[l16], r_fb1=p.flat_b[16+l16];
  float r_vbe0=p.vr_bego[l16], r_vbe1=p.vr_bego[16+l16];
  float r_ln1s=p.ln1_s[i5], r_ln1b=p.ln1_b[i5];
  float r_ln2s=p.ln2_s[i5], r_ln2b=p.ln2_b[i5];
  float r_spls=p.sp_ln_s[i5], r_splb=p.sp_ln_b[i5];
  float r_vrls=p.vr_ln_s[i5], r_vrlb=p.vr_ln_b[i5];
  float r_spw=p.sp_w[i5];
  float r_apwe=p.ap_we[i5];
  float r_apbki=p.ap_bk[i5];
  float r_vwl0=p.vr_wl[i5*2], r_vwl1=p.vr_wl[i5*2+1];
  float r_spb=p.sp_b[0], r_apbe=p.ap_be[0];
  float r_vbl0=p.vr_bl[0], r_vbl1=p.vr_bl[1];
  float r_spt = log1pf(expf(p.sp_lt[0])) + 0.001f;
  int   zc0 = 2*wid*16 + m, zc1 = (2*wid+1)*16 + m;
  float r_zb1c0=p.z_b1[zc0], r_zb1c1=p.z_b1[zc1];
  float r_zb2c0=p.z_b2[zc0], r_zb2c1=p.z_b2[zc1];
  float r_zl1s0=p.z_ln1_s[l], r_zl1s1=p.z_ln1_s[l+64];
  float r_zl1b0=p.z_ln1_b[l], r_zl1b1=p.z_ln1_b[l+64];
  float r_zl2s0=p.z_ln2_s[l], r_zl2s1=p.z_ln2_s[l+64];
  float r_zl2b0=p.z_ln2_b[l], r_zl2b1=p.z_ln2_b[l+64];

  // x load: 198 f32 = 99 float2
  {
    const float2* xr2 = (const float2*)(p.x + (size_t)tok*DX);
    float2* xb2 = (float2*)xb;
    for (int i=l;i<99;i+=64) xb2[i] = xr2[i];
  }
  WF();

  // mask + r/u save (grouped with first MFMAs; consumed after next fence)
  if (l < SLOTS) { int nb = EGO_DD + l*PER;
    mk[l] = (fabsf(xb[nb])>1e-6f || fabsf(xb[nb+1])>1e-6f || fabsf(xb[nb+2])>1e-6f) ? 1 : 0; }
  if (l < 30){ int sl=l/6, d=l%6; ru[l] = xb[EGO_DD + sl*PER + d]; }

  // ---- ego/pair/ter (M=1) raw+bias -> zb[0:160]
  {
    s16x8 aE = packrow(&xb[q*8]);
    s16x8 aP = packrowb(&xb[107], q*8, 10);
    f32x4 e0={0,0,0,0},e1={0,0,0,0},e2={0,0,0,0},e3={0,0,0,0};
    e0=MFMA(aE,BFR(T_EGO+0),e0); e1=MFMA(aE,BFR(T_EGO+1),e1);
    e2=MFMA(aE,BFR(T_EGO+2),e2); e3=MFMA(aE,BFR(T_EGO+3),e3);
    f32x4 p0={0,0,0,0},p1={0,0,0,0};
    p0=MFMA(aP,BFR(T_PAIR+0),p0); p1=MFMA(aP,BFR(T_PAIR+1),p1);
    if (l<16){
      zb[l]    = e0[0]+r_bego0;   zb[16+l] = e1[0]+r_bego1;
      zb[32+l] = e2[0]+r_bego2;   zb[48+l] = e3[0]+r_bego3;
      zb[64+l] = p0[0]+r_bpair0;  zb[80+l] = p1[0]+r_bpair1;
    }
  }
  {
    f32x4 t0={0,0,0,0},t1={0,0,0,0},t2={0,0,0,0},t3={0,0,0,0};
    for(int kt=0;kt<3;kt++){
      s16x8 aT = packrowb(&xb[117], kt*32+q*8, 81);
      t0=MFMA(aT,BFR(T_TER+kt*4+0),t0); t1=MFMA(aT,BFR(T_TER+kt*4+1),t1);
      t2=MFMA(aT,BFR(T_TER+kt*4+2),t2); t3=MFMA(aT,BFR(T_TER+kt*4+3),t3);
    }
    if (l<16){
      zb[96+l] = t0[0]+r_bter0;   zb[112+l]= t1[0]+r_bter1;
      zb[128+l]= t2[0]+r_bter2;   zb[144+l]= t3[0]+r_bter3;
    }
  }
  // ---- invtok (M=16/5) raw+bias -> tv
  {
    int nb = EGO_DD + mm*PER;
    float a0=xb[nb+6],a1=xb[nb+7],a2v=xb[nb+8];
    float nrm = sqrtf(a0*a0+a1*a1+a2v*a2v);
    s16x8 af;
    #pragma unroll
    for(int j=0;j<8;j++){
      int k=q*8+j; float v;
      if(k<6) v=xb[nb+9+k];
      else if(k<9) v=xb[nb+k];
      else if(k==9) v=nrm;
      else v=0.f;
      af[j]=f2bf(v);
    }
    f32x4 c0={0,0,0,0},c1={0,0,0,0};
    c0=MFMA(af,BFR(T_INV+0),c0); c1=MFMA(af,BFR(T_INV+1),c1);
    #pragma unroll
    for(int r=0;r<4;r++){ int row=q*4+r;
      if(row<SLOTS){
        tv[row*ST+m]    = c0[r]+r_binv0;
        tv[row*ST+16+m] = c1[r]+r_binv1;
      }
    }
  }
  WF();
  // mask-derived scalars (mk written before previous fence)
  int nmask = mk[0]+mk[1]+mk[2]+mk[3]+mk[4];
  bool hasany = nmask>0;
  if (l < SLOTS) mks[l] = hasany ? mk[l] : (l==0 ? 1 : 0);
  // zb gelu (vec4) + ego copy
  if (l<40){
    f32x4 v = *(f32x4*)&zb[l*4];
    #pragma unroll
    for(int j=0;j<4;j++) v[j]=gelu_f(v[j]);
    *(f32x4*)&zb[l*4]=v;
    if (l<16) *(f32x4*)&ego[l*4]=v;
  }
  // tv gelu (vec4, masked)
  if (l<40){
    int sl=l>>3, i4=(l&7)*4;
    f32x4 v = *(f32x4*)&tv[sl*ST+i4];
    if (mk[sl]){
      #pragma unroll
      for(int j=0;j<4;j++) v[j]=gelu_f(v[j]);
    } else { v = (f32x4){0.f,0.f,0.f,0.f}; }
    *(f32x4*)&tv[sl*ST+i4]=v;
  }
  WF();   // xb dead from here; U becomes qb/kb/vb

  // ---- LN1 -> bf16 ybh -> qkv
  ln5h(tv, ybh, r_ln1s, r_ln1b, l);
  WF();
  {
    s16x8 aY = *(const s16x8*)&ybh[mm*YHS + q*8];
    f32x4 q0={0,0,0,0},q1={0,0,0,0},k0v={0,0,0,0},k1v={0,0,0,0},v0={0,0,0,0},v1={0,0,0,0};
    q0=MFMA(aY,BFR(T_Q+0),q0);   q1=MFMA(aY,BFR(T_Q+1),q1);
    k0v=MFMA(aY,BFR(T_K+0),k0v); k1v=MFMA(aY,BFR(T_K+1),k1v);
    v0=MFMA(aY,BFR(T_V+0),v0);   v1=MFMA(aY,BFR(T_V+1),v1);
    #pragma unroll
    for(int r=0;r<4;r++){ int row=q*4+r;
      if(row<SLOTS){
        qb[row*ST+m]=q0[r]+r_bq0;     qb[row*ST+16+m]=q1[r]+r_bq1;
        kb[row*ST+m]=k0v[r]+r_bk0;    kb[row*ST+16+m]=k1v[r]+r_bk1;
        vb[row*ST+m]=v0[r]+r_bv0;     vb[row*ST+16+m]=v1[r]+r_bv1;
      }
    }
  }
  WF();
  // attention scores
  for (int t=l; t<100; t+=64){
    int h=t/25, r2=t%25, qs=r2/5, ks=r2%5;
    const f32x4* qp=(const f32x4*)&qb[qs*ST+h*8];
    const f32x4* kp=(const f32x4*)&kb[ks*ST+h*8];
    f32x4 q0=qp[0], q1=qp[1], k0=kp[0], k1=kp[1];
    float d8 = q0[0]*k0[0]+q0[1]*k0[1]+q0[2]*k0[2]+q0[3]*k0[3]
             + q1[0]*k1[0]+q1[1]*k1[1]+q1[2]*k1[2]+q1[3]*k1[3];
    at[t] = (mks[qs]&&mks[ks]) ? d8*0.35355339059327373f : NEGB;
  }
  WF();
  // softmax over ks (20 lanes)
  if (l<20){
    float e[5]; float mx=NEGB, se=0.f;
    #pragma unroll
    for(int ks=0;ks<5;ks++) mx=fmaxf(mx, at[l*5+ks]);
    #pragma unroll
    for(int ks=0;ks<5;ks++){ e[ks]=__expf(at[l*5+ks]-mx); se+=e[ks]; }
    float inv=1.f/se;
    #pragma unroll
    for(int ks=0;ks<5;ks++) at[l*5+ks]=e[ks]*inv;
  }
  WF();
  // attn @ v -> ybh bf16
  if (l<40){
    int sl=l>>3, i4=(l&7)*4, h=i4>>3, d=i4&7;
    f32x4 acc={0.f,0.f,0.f,0.f};
    #pragma unroll
    for(int ks=0;ks<5;ks++){
      float w = at[(h*5+sl)*5+ks];
      f32x4 vv = *(const f32x4*)&vb[ks*ST+h*8+d];
      acc += vv*w;
    }
    s16x4 o;
    #pragma unroll
    for(int j=0;j<4;j++) o[j]=f2bf(acc[j]);
    *(s16x4*)&ybh[sl*YHS+i4]=o;
  }
  WF();
  // wo + residual (zero_masked)
  {
    s16x8 aY = *(const s16x8*)&ybh[mm*YHS + q*8];
    f32x4 c0={0,0,0,0},c1={0,0,0,0};
    c0=MFMA(aY,BFR(T_O+0),c0); c1=MFMA(aY,BFR(T_O+1),c1);
    #pragma unroll
    for(int r=0;r<4;r++){ int row=q*4+r;
      if(row<SLOTS && mk[row]){
        tv[row*ST+m]    += c0[r]+r_bo0;
        tv[row*ST+16+m] += c1[r]+r_bo1;
      }
    }
  }
  WF();
  // LN2 + FFN
  ln5h(tv, ybh, r_ln2s, r_ln2b, l);
  WF();
  {
    s16x8 aY = *(const s16x8*)&ybh[mm*YHS + q*8];
    f32x4 c0={0,0,0,0},c1={0,0,0,0},c2={0,0,0,0},c3={0,0,0,0};
    c0=MFMA(aY,BFR(T_W1+0),c0); c1=MFMA(aY,BFR(T_W1+1),c1);
    c2=MFMA(aY,BFR(T_W1+2),c2); c3=MFMA(aY,BFR(T_W1+3),c3);
    #pragma unroll
    for(int r=0;r<4;r++){ int row=q*4+r;
      if(row<SLOTS){
        hb[row*HBST+m]   =c0[r]+r_b10;
        hb[row*HBST+16+m]=c1[r]+r_b11;
        hb[row*HBST+32+m]=c2[r]+r_b12;
        hb[row*HBST+48+m]=c3[r]+r_b13;
      }
    }
  }
  WF();
  for (int t=l;t<80;t+=64){
    int sl=t>>4, j4=(t&15)*4;
    f32x4 v = *(f32x4*)&hb[sl*HBST+j4];
    s16x4 o;
    #pragma unroll
    for(int j=0;j<4;j++) o[j]=f2bf(gelu_f(v[j]));
    *(s16x4*)&hbh[sl*HHS+j4]=o;
  }
  WF();
  {
    f32x4 c0={0,0,0,0},c1={0,0,0,0};
    for(int kt=0;kt<2;kt++){
      s16x8 aH = *(const s16x8*)&hbh[mm*HHS + kt*32 + q*8];
      c0=MFMA(aH,BFR(T_W2+kt*2+0),c0); c1=MFMA(aH,BFR(T_W2+kt*2+1),c1);
    }
    #pragma unroll
    for(int r=0;r<4;r++){ int row=q*4+r;
      if(row<SLOTS){
        float n0 = mk[row] ? tv[row*ST+m]+c0[r]+r_b20 : 0.f;
        float n1 = mk[row] ? tv[row*ST+16+m]+c1[r]+r_b21 : 0.f;
        tv[row*ST+m]=n0; tv[row*ST+16+m]=n1;
      }
    }
  }
  WF();   // tv final; hb/hbh dead soon

  // ================= TAIL: 6 fence-delimited groups =================
  // GROUP A: independent MFMAs + pools + fused sp/vr LN
  {
    // apq (ego) -> qeb ; vego (ego) -> egh
    f32x4 c0={0,0,0,0},c1={0,0,0,0},d0={0,0,0,0},d1={0,0,0,0};
    for(int kt=0;kt<2;kt++){
      s16x8 aE = packrow(&ego[kt*32 + q*8]);
      c0=MFMA(aE,BFR(T_APQ+kt*2+0),c0); c1=MFMA(aE,BFR(T_APQ+kt*2+1),c1);
      d0=MFMA(aE,BFR(T_VEGO+kt*2+0),d0); d1=MFMA(aE,BFR(T_VEGO+kt*2+1),d1);
    }
    if(l<16){
      qeb[l]=c0[0]+r_apbq0; qeb[16+l]=c1[0]+r_apbq1;
      egh[l]=d0[0]+r_vbe0;  egh[16+l]=d1[0]+r_vbe1;
    }
  }
  {
    // flat (tv, K=160) -> zb[288:320) raw
    f32x4 c0={0,0,0,0},c1={0,0,0,0};
    for(int kt=0;kt<5;kt++){
      s16x8 aF = packrow(&tv[kt*ST + q*8]);
      c0=MFMA(aF,BFR(T_FLAT+kt*2+0),c0); c1=MFMA(aF,BFR(T_FLAT+kt*2+1),c1);
    }
    if(l<16){ zb[288+l]=c0[0]+r_fb0; zb[304+l]=c1[0]+r_fb1; }
  }
  {
    // apk (tv) -> yb raw (bias+qeb added in the fused reduce later)
    s16x8 aT = packrow(&tv[mm*ST + q*8]);
    f32x4 c0={0,0,0,0},c1={0,0,0,0};
    c0=MFMA(aT,BFR(T_APK+0),c0); c1=MFMA(aT,BFR(T_APK+1),c1);
    #pragma unroll
    for(int r=0;r<4;r++){ int row=q*4+r;
      if(row<SLOTS){
        yb[row*ST+m]   =c0[r];
        yb[row*ST+16+m]=c1[r];
      }
    }
  }
  // pools: mean / max
  if (l<32){
    float v0=tv[l],v1=tv[ST+l],v2=tv[2*ST+l],v3=tv[3*ST+l],v4=tv[4*ST+l];
    int cnt = nmask>0?nmask:1;
    zb[160+l]=(v0+v1+v2+v3+v4)/(float)cnt;
    float mx=-1e9f;
    if(mk[0])mx=fmaxf(mx,v0); if(mk[1])mx=fmaxf(mx,v1); if(mk[2])mx=fmaxf(mx,v2);
    if(mk[3])mx=fmaxf(mx,v3); if(mk[4])mx=fmaxf(mx,v4);
    zb[192+l]= hasany ? mx : 0.f;
  }
  // fused LN: vr-LN -> ath bf16; sp scores -> scs
  ln5_spvr(tv, ath, scs, r_spls, r_splb, r_vrls, r_vrlb, r_spw, r_spb, l);
  WF();

  // GROUP B: sp softmax; flat gelu; ap fused tanh-reduce; vh MFMA
  if (l<8){
    bool keep=(l<5)&&(mk[l]!=0);
    float x= keep? r_spt*scs[l] : NEGB;
    float mx=x;
    mx=fmaxf(mx,__shfl_xor(mx,1,8)); mx=fmaxf(mx,__shfl_xor(mx,2,8)); mx=fmaxf(mx,__shfl_xor(mx,4,8));
    float e= keep? __expf(x-mx):0.f;
    float se=e;
    se+=__shfl_xor(se,1,8); se+=__shfl_xor(se,2,8); se+=__shfl_xor(se,4,8);
    if (l<5) wts[l]= se>0.f? e/se:0.f;
  }
  if(l<32) zb[288+l]=0.25f*gelu_f(zb[288+l]);
  // ap score: tanh fused into the reduce
  for (int sp=0; sp<6; sp+=2){
    int sl = sp + (l>>5), i = l&31;
    float v = (sl<SLOTS) ? tanh_f(yb[sl*ST+i]+r_apbki+qeb[i])*r_apwe : 0.f;
    v=red5(v);
    if (sl<SLOTS && i==0) aps[sl]=v+r_apbe;
  }
  {
    // vh: A=[vr-LN(ath) | ego_h(egh)] -> vq raw (+bias)
    s16x8 aY = *(const s16x8*)&ath[mm*YHS + q*8];
    s16x8 aE = packrow(&egh[q*8]);
    f32x4 c0={0,0,0,0},c1={0,0,0,0};
    c0=MFMA(aY,BFR(T_VH+0),c0); c1=MFMA(aY,BFR(T_VH+1),c1);
    c0=MFMA(aE,BFR(T_VH+2),c0); c1=MFMA(aE,BFR(T_VH+3),c1);
    #pragma unroll
    for(int r=0;r<4;r++){ int row=q*4+r;
      if(row<SLOTS){
        vq[row*ST+m]   =c0[r]+r_vbh0;
        vq[row*ST+16+m]=c1[r]+r_vbh1;
      }
    }
  }
  WF();

  // GROUP C: sp wsum; ap softmax; vr logits (gelu fused)
  if (l<32){ float a=0;
    for(int sl=0;sl<5;sl++) a += wts[sl]*tv[sl*ST+l];
    zb[224+l]=a; }
  if (l<8){
    bool keep=(l<5)&&(mk[l]!=0);
    float x= keep? aps[l] : NEGB;
    float mx=x;
    mx=fmaxf(mx,__shfl_xor(mx,1,8)); mx=fmaxf(mx,__shfl_xor(mx,2,8)); mx=fmaxf(mx,__shfl_xor(mx,4,8));
    float e= keep? __expf(x-mx):0.f;
    float se=e;
    se+=__shfl_xor(se,1,8); se+=__shfl_xor(se,2,8); se+=__shfl_xor(se,4,8);
    if (l<5) alp[l]= se>0.f? e/se:0.f;
  }
  for (int t=0; t<5; t++){
    int hh = l>>5, sl = t, i = l&31;
    float g = gelu_f(vq[sl*ST+i]);
    float v = g*(hh? r_vwl1 : r_vwl0);
    v=red5(v);
    if (i==0) lg[sl*2+hh]=v+(hh? r_vbl1 : r_vbl0);
  }
  WF();

  // GROUP D: ap wsum; vr softmax (2 rows, 8-lane groups)
  if (l<32){ float a=0;
    for(int sl=0;sl<5;sl++) a += alp[sl]*tv[sl*ST+l];
    zb[256+l]=a; }
  if (l<16){
    int s=l&7, hh=l>>3;
    bool keep=(s<5)&&(mk[s<5?s:0]!=0);
    float x= keep? lg[(s<5?s:0)*2+hh] : NEGB;
    float mx=x;
    mx=fmaxf(mx,__shfl_xor(mx,1,8)); mx=fmaxf(mx,__shfl_xor(mx,2,8)); mx=fmaxf(mx,__shfl_xor(mx,4,8));
    float e= keep? __expf(x-mx):0.f;
    float se=e;
    se+=__shfl_xor(se,1,8); se+=__shfl_xor(se,2,8); se+=__shfl_xor(se,4,8);
    if (s<5) a2[s*2+hh]= se>0.f? e/se:0.f;
  }
  WF();

  // GROUP E: v_r / v_u tail
  if (l<12){ int w = l/6, rem=l%6, hh=rem/3, d=rem%3;
    float a=0;
    for(int sl=0;sl<5;sl++) a += a2[sl*2+hh]*ru[sl*6 + w*3 + d];
    zb[320 + w*6 + hh*3 + d]=a; }
  WF();   // z[332] complete; U dead; U becomes z-phase overlay

  // convert own zb -> bf16 zbh
  {
    short* zbh = (short*)(W + OF_U + 300);
    for (int t=l;t<88;t+=64){
      s16x4 o;
      if (t<83){
        f32x4 v = *(const f32x4*)&zb[t*4];
        #pragma unroll
        for(int j=0;j<4;j++) o[j]=f2bf(v[j]);
      } else {
        #pragma unroll
        for(int j=0;j<4;j++) o[j]=0;
      }
      *(s16x4*)&zbh[t*4]=o;
    }
  }
  __syncthreads();   // cross-wave: all 4 tokens' zbh needed below

  // ---- fused z-phase (MFMA): GEMM1 K=352
  {
    f32x4 acc0 = {0.f,0.f,0.f,0.f}, acc1 = {0.f,0.f,0.f,0.f};
    const short* zbhM = (const short*)(pool + (m<4?m:0)*PW + OF_U + 300);
    for (int kt=0; kt<11; kt++){
      s16x8 af;
      if (m < 4) af = *(const s16x8*)&zbhM[kt*32 + q*8];
      else {
        #pragma unroll
        for (int j=0;j<8;j++) af[j]=0;
      }
      s16x8 b0 = wsv[(T_ZW1 + kt*8 + 2*wid  )*64 + l];
      s16x8 b1 = wsv[(T_ZW1 + kt*8 + 2*wid+1)*64 + l];
      acc0 = MFMA(af, b0, acc0);
      acc1 = MFMA(af, b1, acc1);
    }
    if (q == 0){
      #pragma unroll
      for (int r=0;r<4;r++){
        pool[r*PW + OF_U + zc0] = gelu_f(acc0[r] + r_zb1c0);   // h1
        pool[r*PW + OF_U + zc1] = gelu_f(acc1[r] + r_zb1c1);
      }
    }
  }
  __syncthreads();
  // LN1 on own token's h1 -> h1h (bf16)
  {
    float v0 = pool[wid*PW + OF_U + l], v1 = pool[wid*PW + OF_U + l+64];
    float sum = v0+v1, qq = v0*v0+v1*v1;
    for (int o=32;o>=1;o>>=1){ sum += __shfl_xor(sum,o,64); qq += __shfl_xor(qq,o,64); }
    float mu = sum*(1.f/128.f);
    float rs = rsqrtf(qq*(1.f/128.f)-mu*mu+1e-6f);
    short* h1h = (short*)(W + OF_U + 476);
    h1h[l]    = f2bf((v0-mu)*rs*r_zl1s0+r_zl1b0);
    h1h[l+64] = f2bf((v1-mu)*rs*r_zl1s1+r_zl1b1);
  }
  __syncthreads();
  // GEMM2 K=128
  {
    f32x4 acc0 = {0.f,0.f,0.f,0.f}, acc1 = {0.f,0.f,0.f,0.f};
    const short* h1hM = (const short*)(pool + (m<4?m:0)*PW + OF_U + 476);
    for (int kt=0; kt<4; kt++){
      s16x8 af;
      if (m < 4) af = *(const s16x8*)&h1hM[kt*32 + q*8];
      else {
        #pragma unroll
        for (int j=0;j<8;j++) af[j]=0;
      }
      s16x8 b0 = wsv[(T_ZW2 + kt*8 + 2*wid  )*64 + l];
      s16x8 b1 = wsv[(T_ZW2 + kt*8 + 2*wid+1)*64 + l];
      acc0 = MFMA(af, b0, acc0);
      acc1 = MFMA(af, b1, acc1);
    }
    if (q == 0){
      #pragma unroll
      for (int r=0;r<4;r++){
        pool[r*PW + OF_U + 128 + zc0] = gelu_f(acc0[r] + r_zb2c0);   // h2
        pool[r*PW + OF_U + 128 + zc1] = gelu_f(acc1[r] + r_zb2c1);
      }
    }
  }
  __syncthreads();
  // LN2 per wave + store
  {
    float v0 = pool[wid*PW + OF_U + 128 + l], v1 = pool[wid*PW + OF_U + 128 + l+64];
    float sum = v0+v1, qq = v0*v0+v1*v1;
    for (int o=32;o>=1;o>>=1){ sum += __shfl_xor(sum,o,64); qq += __shfl_xor(qq,o,64); }
    float mu = sum*(1.f/128.f);
    float rs = rsqrtf(qq*(1.f/128.f)-mu*mu+1e-6f);
    float o0 = (v0-mu)*rs*r_zl2s0+r_zl2b0;
    float o1 = (v1-mu)*rs*r_zl2s1+r_zl2b1;
    float* op = outp + (size_t)tok*128;
    op[l]    = o0;
    op[l+64] = o1;
  }
}

extern "C" void kernel_launch(void* const* d_in, const int* in_sizes, int n_in,
                              void* d_out, int out_size, void* d_ws, size_t ws_size,
                              hipStream_t stream) {
  (void)in_sizes; (void)n_in; (void)out_size; (void)ws_size;
  P p;
  const void** pp = (const void**)&p;
  for (int i=0;i<54;i++) pp[i] = d_in[i];
  short* wsb = (short*)d_ws;   // 184320 B needed
  k_prep<<<(T_TOT*512+255)/256, 256, 0, stream>>>(p, wsb);
  k_token<<<NTOK/WV, 256, 0, stream>>>(p, (float*)d_out, wsb);
}

// Round 4
// 1166.751 us; speedup vs baseline: 1.4077x; 1.4077x over previous
//
#include <hip/hip_runtime.h>
#include <hip/hip_bf16.h>

#define SLOTS 5
#define PER 15
#define EGO_DD 32
#define PAIR_DD 10
#define TER_DD 81
#define DX 198
#define ZDIM 332
#define NTOK (64*2048)
#define NEGB (-3.402823466e38f)
#define ST 36      // padded stride for [5][32] f32 slot arrays
#define HBST 68    // padded stride for [5][64] f32 ffn hidden
#define YHS 40     // padded stride (shorts) for bf16 [5][32]
#define HHS 72     // padded stride (shorts) for bf16 [5][64]

// ---- B-fragment tile table ----
#define T_EGO   0
#define T_PAIR  4
#define T_TER   6
#define T_INV   18
#define T_Q     20
#define T_K     22
#define T_V     24
#define T_O     26
#define T_W1    28
#define T_W2    32
#define T_APQ   36
#define T_APK   40
#define T_FLAT  42
#define T_VEGO  52
#define T_VH    56
#define T_ZW1   60
#define T_ZW2   148
#define T_TOT   180
#define WS_NEED (T_TOT*512*2)

// ---- per-wave LDS pool layout (floats), PW = 1540 ----
#define PW 1540
#define OF_EGO 0
#define OF_TV  64
#define OF_YB  244
#define OF_U   424
#define OF_AT  964
#define OF_ZB  1064
#define OF_QEB 1396
#define OF_EGH 1428
#define OF_RU  1460
#define OF_SM  1492

typedef float f32x4 __attribute__((ext_vector_type(4)));
typedef short s16x8 __attribute__((ext_vector_type(8)));
typedef short s16x4 __attribute__((ext_vector_type(4)));
#define MFMA(a,b,c) __builtin_amdgcn_mfma_f32_16x16x32_bf16(a,b,c,0,0,0)
// Intra-wave phase separator: compiler memory fence only (same-wave LDS is
// ordered in HW; cross-wave data only at the z-phase barriers).
#define WF() asm volatile("" ::: "memory")

struct P {
  const float *x,*w_ego,*b_ego,*w_pair,*b_pair,*w_ter,*b_ter,*w_invtok,*b_invtok,
    *ln1_s,*ln1_b,*wq,*bq,*wk,*bk,*wv,*bv,*wo,*bo,*ln2_s,*ln2_b,*w1,*b1,*w2,*b2,
    *sp_ln_s,*sp_ln_b,*sp_w,*sp_b,*sp_lt,*ap_wq,*ap_bq,*ap_wk,*ap_bk,*ap_we,*ap_be,
    *flat_w,*flat_b,*vr_wego,*vr_bego,*vr_ln_s,*vr_ln_b,*vr_wh,*vr_bh,*vr_wl,*vr_bl,
    *z_w1,*z_b1,*z_ln1_s,*z_ln1_b,*z_w2,*z_b2,*z_ln2_s,*z_ln2_b;
};

__device__ __forceinline__ short f2bf(float x){
  __hip_bfloat16 h = __float2bfloat16(x);
  return *reinterpret_cast<short*>(&h);
}
__device__ __forceinline__ float tanh_f(float x){
  float e = __expf(2.f*x);
  return 1.f - 2.f/(e+1.f);
}
__device__ __forceinline__ float gelu_f(float x){
  return 0.5f*x*(1.f+tanh_f(0.7978845608028654f*(x + 0.044715f*x*x*x)));
}
__device__ __forceinline__ s16x8 packrow(const float* r){
  s16x8 af;
  #pragma unroll
  for(int j=0;j<8;j++) af[j]=f2bf(r[j]);
  return af;
}
__device__ __forceinline__ s16x8 packrowb(const float* r, int k0, int K){
  s16x8 af;
  #pragma unroll
  for(int j=0;j<8;j++) af[j] = (k0+j<K) ? f2bf(r[k0+j]) : (short)0;
  return af;
}

// dual interleaved 32-lane reduce (two independent chains pipeline)
__device__ __forceinline__ void red5_2(float&a,float&b){
  a+=__shfl_xor(a,16,32); b+=__shfl_xor(b,16,32);
  a+=__shfl_xor(a,8,32);  b+=__shfl_xor(b,8,32);
  a+=__shfl_xor(a,4,32);  b+=__shfl_xor(b,4,32);
  a+=__shfl_xor(a,2,32);  b+=__shfl_xor(b,2,32);
  a+=__shfl_xor(a,1,32);  b+=__shfl_xor(b,1,32);
}
__device__ __forceinline__ float red5(float a){
  a+=__shfl_xor(a,16,32); a+=__shfl_xor(a,8,32); a+=__shfl_xor(a,4,32);
  a+=__shfl_xor(a,2,32);  a+=__shfl_xor(a,1,32);
  return a;
}

// LayerNorm (dual-tree) -> bf16 dst (stride YHS)
__device__ void ln5x32h(const float* src, short* dst, const float* Sc, const float* Bi, int l){
  for (int sp=0; sp<6; sp+=2){
    int sl = sp + (l>>5), i = l&31;
    bool act = sl < SLOTS;
    float v = act ? src[sl*ST+i] : 0.f;
    float s=v, ss=v*v;
    red5_2(s,ss);
    float mu=s*(1.f/32.f);
    float rstd=rsqrtf(ss*(1.f/32.f)-mu*mu+1e-6f);
    if(act) dst[sl*YHS+i]=f2bf((v-mu)*rstd*Sc[i]+Bi[i]);
  }
}
// fused sp+vr LN on the same src (same mu/rstd!): vr -> bf16 ath; sp scores -> scs
__device__ void ln5_spvr(const float* src, short* ath, float* scs,
    const float* sps, const float* spb, const float* vrs, const float* vrb,
    const float* spw, float spbias, int l){
  for (int sp=0; sp<6; sp+=2){
    int sl = sp + (l>>5), i = l&31;
    bool act = sl < SLOTS;
    float v = act ? src[sl*ST+i] : 0.f;
    float s=v, ss=v*v;
    red5_2(s,ss);
    float mu=s*(1.f/32.f);
    float rstd=rsqrtf(ss*(1.f/32.f)-mu*mu+1e-6f);
    float d=(v-mu)*rstd;
    if(act) ath[sl*YHS+i]=f2bf(d*vrs[i]+vrb[i]);
    float t=(d*sps[i]+spb[i])*spw[i];
    t=red5(t);
    if(act && i==0) scs[sl]=t+spbias;
  }
}

// pack all weights into bf16 B-fragments
__global__ __launch_bounds__(256) void k_prep(P p, short* __restrict__ ws){
  int idx = blockIdx.x*256 + threadIdx.x;
  if (idx >= T_TOT*512) return;
  int j = idx & 7, lane = (idx>>3)&63, tile = idx>>9;
  const float* src; int K,N,ntc,t0;
  if      (tile < T_PAIR){ src=p.w_ego;   K=32;  N=64;  ntc=4; t0=T_EGO; }
  else if (tile < T_TER ){ src=p.w_pair;  K=10;  N=32;  ntc=2; t0=T_PAIR; }
  else if (tile < T_INV ){ src=p.w_ter;   K=81;  N=64;  ntc=4; t0=T_TER; }
  else if (tile < T_Q   ){ src=p.w_invtok;K=10;  N=32;  ntc=2; t0=T_INV; }
  else if (tile < T_K   ){ src=p.wq;      K=32;  N=32;  ntc=2; t0=T_Q; }
  else if (tile < T_V   ){ src=p.wk;      K=32;  N=32;  ntc=2; t0=T_K; }
  else if (tile < T_O   ){ src=p.wv;      K=32;  N=32;  ntc=2; t0=T_V; }
  else if (tile < T_W1  ){ src=p.wo;      K=32;  N=32;  ntc=2; t0=T_O; }
  else if (tile < T_W2  ){ src=p.w1;      K=32;  N=64;  ntc=4; t0=T_W1; }
  else if (tile < T_APQ ){ src=p.w2;      K=64;  N=32;  ntc=2; t0=T_W2; }
  else if (tile < T_APK ){ src=p.ap_wq;   K=64;  N=32;  ntc=2; t0=T_APQ; }
  else if (tile < T_FLAT){ src=p.ap_wk;   K=32;  N=32;  ntc=2; t0=T_APK; }
  else if (tile < T_VEGO){ src=p.flat_w;  K=160; N=32;  ntc=2; t0=T_FLAT; }
  else if (tile < T_VH  ){ src=p.vr_wego; K=64;  N=32;  ntc=2; t0=T_VEGO; }
  else if (tile < T_ZW1 ){ src=p.vr_wh;   K=64;  N=32;  ntc=2; t0=T_VH; }
  else if (tile < T_ZW2 ){ src=p.z_w1;    K=ZDIM;N=128; ntc=8; t0=T_ZW1; }
  else                   { src=p.z_w2;    K=128; N=128; ntc=8; t0=T_ZW2; }
  int tl = tile - t0, ktI = tl/ntc, ntI = tl%ntc;
  int k = ktI*32 + ((lane>>4)<<3) + j, n = ntI*16 + (lane&15);
  float v = (k<K && n<N) ? src[k*N+n] : 0.f;
  ws[idx] = f2bf(v);
}

#define WV 4
__global__ __launch_bounds__(256) void k_token(P p, float* __restrict__ outp,
                                               const short* __restrict__ wsb) {
  __shared__ __align__(16) float pool[WV*PW];
  __shared__ int mkA[WV][5];
  __shared__ int mksA[WV][5];
  const s16x8* wsv = (const s16x8*)wsb;
  int wid = threadIdx.x >> 6, l = threadIdx.x & 63;
  float* W   = pool + wid*PW;
  float* ego = W + OF_EGO;
  float* tv  = W + OF_TV;
  float* yb  = W + OF_YB;                 // f32 view (ap raw scores)
  short* ybh = (short*)(W + OF_YB);       // bf16 view (LN1/LN2/attn-y)
  float* U   = W + OF_U;
  float* at  = W + OF_AT;
  short* ath = (short*)(W + OF_AT);       // vr-LN bf16 (at region, post-attention)
  float* zb  = W + OF_ZB;
  float* qeb = W + OF_QEB;
  float* egh = W + OF_EGH;
  float* ru  = W + OF_RU;
  float* sm  = W + OF_SM;
  float* scs = sm+0; float* wts = sm+5; float* alp = sm+10; float* lg = sm+16;
  float* a2 = sm+26; float* aps = sm+36;
  int* mk  = mkA[wid];
  int* mks = mksA[wid];
  // U overlays
  float* xb = U;                // phase A
  float* qb = U;  float* kb = U+180;  float* vb = U+360;   // phase B
  float* hb = U;                                            // phase C (f32 raw)
  short* hbh = (short*)(U + 344);                            // phase C (bf16 gelu'd)
  float* vq = U;                // tail: vh raw output
  long tok = (long)blockIdx.x*WV + wid;
  int m = l & 15, q = l >> 4;
  int mm = m < 5 ? m : 4;
#define BFR(tile) wsv[(tile)*64 + l]

  // x load: 198 f32 = 99 float2
  {
    const float2* xr2 = (const float2*)(p.x + (size_t)tok*DX);
    float2* xb2 = (float2*)xb;
    for (int i=l;i<99;i+=64) xb2[i] = xr2[i];
  }
  WF();

  // mask from r = nbr[...,0:3]
  if (l < SLOTS) { int nb = EGO_DD + l*PER;
    mk[l] = (fabsf(xb[nb])>1e-6f || fabsf(xb[nb+1])>1e-6f || fabsf(xb[nb+2])>1e-6f) ? 1 : 0; }
  // save r/u for final z-tail (xb will be overwritten)
  if (l < 30){ int sl=l/6, d=l%6; ru[l] = xb[EGO_DD + sl*PER + d]; }
  WF();
  int nmask = mk[0]+mk[1]+mk[2]+mk[3]+mk[4];
  bool hasany = nmask>0;
  if (l < SLOTS) mks[l] = hasany ? mk[l] : (l==0 ? 1 : 0);

  // ---- ego/pair/ter (M=1) raw+bias -> zb[0:160]
  {
    s16x8 aE = packrow(&xb[q*8]);
    s16x8 aP = packrowb(&xb[107], q*8, 10);
    f32x4 e0={0,0,0,0},e1={0,0,0,0},e2={0,0,0,0},e3={0,0,0,0};
    e0=MFMA(aE,BFR(T_EGO+0),e0); e1=MFMA(aE,BFR(T_EGO+1),e1);
    e2=MFMA(aE,BFR(T_EGO+2),e2); e3=MFMA(aE,BFR(T_EGO+3),e3);
    f32x4 p0={0,0,0,0},p1={0,0,0,0};
    p0=MFMA(aP,BFR(T_PAIR+0),p0); p1=MFMA(aP,BFR(T_PAIR+1),p1);
    if (l<16){
      zb[l]    = e0[0]+p.b_ego[l];    zb[16+l] = e1[0]+p.b_ego[16+l];
      zb[32+l] = e2[0]+p.b_ego[32+l]; zb[48+l] = e3[0]+p.b_ego[48+l];
      zb[64+l] = p0[0]+p.b_pair[l];   zb[80+l] = p1[0]+p.b_pair[16+l];
    }
  }
  {
    f32x4 t0={0,0,0,0},t1={0,0,0,0},t2={0,0,0,0},t3={0,0,0,0};
    for(int kt=0;kt<3;kt++){
      s16x8 aT = packrowb(&xb[117], kt*32+q*8, 81);
      t0=MFMA(aT,BFR(T_TER+kt*4+0),t0); t1=MFMA(aT,BFR(T_TER+kt*4+1),t1);
      t2=MFMA(aT,BFR(T_TER+kt*4+2),t2); t3=MFMA(aT,BFR(T_TER+kt*4+3),t3);
    }
    if (l<16){
      zb[96+l] = t0[0]+p.b_ter[l];    zb[112+l]= t1[0]+p.b_ter[16+l];
      zb[128+l]= t2[0]+p.b_ter[32+l]; zb[144+l]= t3[0]+p.b_ter[48+l];
    }
  }
  // ---- invtok (M=16/5) raw+bias -> tv
  {
    int nb = EGO_DD + mm*PER;
    float a0=xb[nb+6],a1=xb[nb+7],a2v=xb[nb+8];
    float nrm = sqrtf(a0*a0+a1*a1+a2v*a2v);
    s16x8 af;
    #pragma unroll
    for(int j=0;j<8;j++){
      int k=q*8+j; float v;
      if(k<6) v=xb[nb+9+k];
      else if(k<9) v=xb[nb+k];
      else if(k==9) v=nrm;
      else v=0.f;
      af[j]=f2bf(v);
    }
    f32x4 c0={0,0,0,0},c1={0,0,0,0};
    c0=MFMA(af,BFR(T_INV+0),c0); c1=MFMA(af,BFR(T_INV+1),c1);
    #pragma unroll
    for(int r=0;r<4;r++){ int row=q*4+r;
      if(row<SLOTS){
        tv[row*ST+m]    = c0[r]+p.b_invtok[m];
        tv[row*ST+16+m] = c1[r]+p.b_invtok[16+m];
      }
    }
  }
  WF();
  // zb gelu (vec4) + ego copy
  if (l<40){
    f32x4 v = *(f32x4*)&zb[l*4];
    #pragma unroll
    for(int j=0;j<4;j++) v[j]=gelu_f(v[j]);
    *(f32x4*)&zb[l*4]=v;
    if (l<16) *(f32x4*)&ego[l*4]=v;
  }
  // tv gelu (vec4, masked)
  if (l<40){
    int sl=l>>3, i4=(l&7)*4;
    f32x4 v = *(f32x4*)&tv[sl*ST+i4];
    if (mk[sl]){
      #pragma unroll
      for(int j=0;j<4;j++) v[j]=gelu_f(v[j]);
    } else { v = (f32x4){0.f,0.f,0.f,0.f}; }
    *(f32x4*)&tv[sl*ST+i4]=v;
  }
  WF();   // xb dead from here; U becomes qb/kb/vb

  // ---- LN1 -> bf16 ybh -> qkv
  ln5x32h(tv, ybh, p.ln1_s, p.ln1_b, l);
  WF();
  {
    s16x8 aY = *(const s16x8*)&ybh[mm*YHS + q*8];
    f32x4 q0={0,0,0,0},q1={0,0,0,0},k0v={0,0,0,0},k1v={0,0,0,0},v0={0,0,0,0},v1={0,0,0,0};
    q0=MFMA(aY,BFR(T_Q+0),q0);   q1=MFMA(aY,BFR(T_Q+1),q1);
    k0v=MFMA(aY,BFR(T_K+0),k0v); k1v=MFMA(aY,BFR(T_K+1),k1v);
    v0=MFMA(aY,BFR(T_V+0),v0);   v1=MFMA(aY,BFR(T_V+1),v1);
    #pragma unroll
    for(int r=0;r<4;r++){ int row=q*4+r;
      if(row<SLOTS){
        qb[row*ST+m]=q0[r]+p.bq[m];     qb[row*ST+16+m]=q1[r]+p.bq[16+m];
        kb[row*ST+m]=k0v[r]+p.bk[m];    kb[row*ST+16+m]=k1v[r]+p.bk[16+m];
        vb[row*ST+m]=v0[r]+p.bv[m];     vb[row*ST+16+m]=v1[r]+p.bv[16+m];
      }
    }
  }
  WF();
  // attention scores
  for (int t=l; t<100; t+=64){
    int h=t/25, r2=t%25, qs=r2/5, ks=r2%5;
    const f32x4* qp=(const f32x4*)&qb[qs*ST+h*8];
    const f32x4* kp=(const f32x4*)&kb[ks*ST+h*8];
    f32x4 q0=qp[0], q1=qp[1], k0=kp[0], k1=kp[1];
    float d8 = q0[0]*k0[0]+q0[1]*k0[1]+q0[2]*k0[2]+q0[3]*k0[3]
             + q1[0]*k1[0]+q1[1]*k1[1]+q1[2]*k1[2]+q1[3]*k1[3];
    at[t] = (mks[qs]&&mks[ks]) ? d8*0.35355339059327373f : NEGB;
  }
  WF();
  // softmax over ks (20 lanes)
  if (l<20){
    float e[5]; float mx=NEGB, se=0.f;
    #pragma unroll
    for(int ks=0;ks<5;ks++) mx=fmaxf(mx, at[l*5+ks]);
    #pragma unroll
    for(int ks=0;ks<5;ks++){ e[ks]=__expf(at[l*5+ks]-mx); se+=e[ks]; }
    float inv=1.f/se;
    #pragma unroll
    for(int ks=0;ks<5;ks++) at[l*5+ks]=e[ks]*inv;
  }
  WF();
  // attn @ v -> ybh bf16
  if (l<40){
    int sl=l>>3, i4=(l&7)*4, h=i4>>3, d=i4&7;
    f32x4 acc={0.f,0.f,0.f,0.f};
    #pragma unroll
    for(int ks=0;ks<5;ks++){
      float w = at[(h*5+sl)*5+ks];
      f32x4 vv = *(const f32x4*)&vb[ks*ST+h*8+d];
      acc += vv*w;
    }
    s16x4 o;
    #pragma unroll
    for(int j=0;j<4;j++) o[j]=f2bf(acc[j]);
    *(s16x4*)&ybh[sl*YHS+i4]=o;
  }
  WF();
  // wo + residual (zero_masked)
  {
    s16x8 aY = *(const s16x8*)&ybh[mm*YHS + q*8];
    f32x4 c0={0,0,0,0},c1={0,0,0,0};
    c0=MFMA(aY,BFR(T_O+0),c0); c1=MFMA(aY,BFR(T_O+1),c1);
    #pragma unroll
    for(int r=0;r<4;r++){ int row=q*4+r;
      if(row<SLOTS && mk[row]){
        tv[row*ST+m]    += c0[r]+p.bo[m];
        tv[row*ST+16+m] += c1[r]+p.bo[16+m];
      }
    }
  }
  WF();
  // LN2 + FFN
  ln5x32h(tv, ybh, p.ln2_s, p.ln2_b, l);
  WF();
  {
    s16x8 aY = *(const s16x8*)&ybh[mm*YHS + q*8];
    f32x4 c0={0,0,0,0},c1={0,0,0,0},c2={0,0,0,0},c3={0,0,0,0};
    c0=MFMA(aY,BFR(T_W1+0),c0); c1=MFMA(aY,BFR(T_W1+1),c1);
    c2=MFMA(aY,BFR(T_W1+2),c2); c3=MFMA(aY,BFR(T_W1+3),c3);
    #pragma unroll
    for(int r=0;r<4;r++){ int row=q*4+r;
      if(row<SLOTS){
        hb[row*HBST+m]   =c0[r]+p.b1[m];
        hb[row*HBST+16+m]=c1[r]+p.b1[16+m];
        hb[row*HBST+32+m]=c2[r]+p.b1[32+m];
        hb[row*HBST+48+m]=c3[r]+p.b1[48+m];
      }
    }
  }
  WF();
  for (int t=l;t<80;t+=64){
    int sl=t>>4, j4=(t&15)*4;
    f32x4 v = *(f32x4*)&hb[sl*HBST+j4];
    s16x4 o;
    #pragma unroll
    for(int j=0;j<4;j++) o[j]=f2bf(gelu_f(v[j]));
    *(s16x4*)&hbh[sl*HHS+j4]=o;
  }
  WF();
  {
    f32x4 c0={0,0,0,0},c1={0,0,0,0};
    for(int kt=0;kt<2;kt++){
      s16x8 aH = *(const s16x8*)&hbh[mm*HHS + kt*32 + q*8];
      c0=MFMA(aH,BFR(T_W2+kt*2+0),c0); c1=MFMA(aH,BFR(T_W2+kt*2+1),c1);
    }
    #pragma unroll
    for(int r=0;r<4;r++){ int row=q*4+r;
      if(row<SLOTS){
        float n0 = mk[row] ? tv[row*ST+m]+c0[r]+p.b2[m] : 0.f;
        float n1 = mk[row] ? tv[row*ST+16+m]+c1[r]+p.b2[16+m] : 0.f;
        tv[row*ST+m]=n0; tv[row*ST+16+m]=n1;
      }
    }
  }
  WF();   // tv final

  // pools: mean / max
  if (l<32){
    float v0=tv[l],v1=tv[ST+l],v2=tv[2*ST+l],v3=tv[3*ST+l],v4=tv[4*ST+l];
    int cnt = nmask>0?nmask:1;
    zb[160+l]=(v0+v1+v2+v3+v4)/(float)cnt;
    float mx=-1e9f;
    if(mk[0])mx=fmaxf(mx,v0); if(mk[1])mx=fmaxf(mx,v1); if(mk[2])mx=fmaxf(mx,v2);
    if(mk[3])mx=fmaxf(mx,v3); if(mk[4])mx=fmaxf(mx,v4);
    zb[192+l]= hasany ? mx : 0.f;
  }
  // fused sp+vr LN: vr-LN -> ath bf16; sp scores -> scs
  ln5_spvr(tv, ath, scs, p.sp_ln_s, p.sp_ln_b, p.vr_ln_s, p.vr_ln_b,
           p.sp_w, p.sp_b[0], l);
  WF();
  // sp softmax (8-lane parallel)
  if (l<8){
    float temp = log1pf(expf(p.sp_lt[0])) + 0.001f;
    bool keep=(l<5)&&(mk[l]!=0);
    float x= keep? temp*scs[l] : NEGB;
    float mx=x;
    mx=fmaxf(mx,__shfl_xor(mx,1,8)); mx=fmaxf(mx,__shfl_xor(mx,2,8)); mx=fmaxf(mx,__shfl_xor(mx,4,8));
    float e= keep? __expf(x-mx):0.f;
    float se=e;
    se+=__shfl_xor(se,1,8); se+=__shfl_xor(se,2,8); se+=__shfl_xor(se,4,8);
    if (l<5) wts[l]= se>0.f? e/se:0.f;
  }
  WF();
  // sp wsum
  if (l<32){ float a=0;
    for(int sl=0;sl<5;sl++) a += wts[sl]*tv[sl*ST+l];
    zb[224+l]=a; }
  // ap_wq (M=1, K=64) -> qeb
  {
    f32x4 c0={0,0,0,0},c1={0,0,0,0};
    for(int kt=0;kt<2;kt++){
      s16x8 aE = packrow(&ego[kt*32 + q*8]);
      c0=MFMA(aE,BFR(T_APQ+kt*2+0),c0); c1=MFMA(aE,BFR(T_APQ+kt*2+1),c1);
    }
    if(l<16){ qeb[l]=c0[0]+p.ap_bq[l]; qeb[16+l]=c1[0]+p.ap_bq[16+l]; }
  }
  WF();
  // ap_wk + qeb -> yb (raw, pre-tanh)
  {
    s16x8 aT = packrow(&tv[mm*ST + q*8]);
    f32x4 c0={0,0,0,0},c1={0,0,0,0};
    c0=MFMA(aT,BFR(T_APK+0),c0); c1=MFMA(aT,BFR(T_APK+1),c1);
    #pragma unroll
    for(int r=0;r<4;r++){ int row=q*4+r;
      if(row<SLOTS){
        yb[row*ST+m]   =c0[r]+p.ap_bk[m]+qeb[m];
        yb[row*ST+16+m]=c1[r]+p.ap_bk[16+m]+qeb[16+m];
      }
    }
  }
  WF();
  // ap score: tanh fused into the reduce
  for (int sp=0; sp<6; sp+=2){
    int sl = sp + (l>>5), i = l&31;
    float v = (sl<SLOTS) ? tanh_f(yb[sl*ST+i])*p.ap_we[i] : 0.f;
    v=red5(v);
    if (sl<SLOTS && i==0) aps[sl]=v+p.ap_be[0];
  }
  WF();
  // ap softmax (8-lane parallel)
  if (l<8){
    bool keep=(l<5)&&(mk[l]!=0);
    float x= keep? aps[l] : NEGB;
    float mx=x;
    mx=fmaxf(mx,__shfl_xor(mx,1,8)); mx=fmaxf(mx,__shfl_xor(mx,2,8)); mx=fmaxf(mx,__shfl_xor(mx,4,8));
    float e= keep? __expf(x-mx):0.f;
    float se=e;
    se+=__shfl_xor(se,1,8); se+=__shfl_xor(se,2,8); se+=__shfl_xor(se,4,8);
    if (l<5) alp[l]= se>0.f? e/se:0.f;
  }
  WF();
  // ap wsum; flat; vego
  if (l<32){ float a=0;
    for(int sl=0;sl<5;sl++) a += alp[sl]*tv[sl*ST+l];
    zb[256+l]=a; }
  {
    f32x4 c0={0,0,0,0},c1={0,0,0,0};
    for(int kt=0;kt<5;kt++){
      s16x8 aF = packrow(&tv[kt*ST + q*8]);
      c0=MFMA(aF,BFR(T_FLAT+kt*2+0),c0); c1=MFMA(aF,BFR(T_FLAT+kt*2+1),c1);
    }
    if(l<16){ zb[288+l]=c0[0]+p.flat_b[l]; zb[304+l]=c1[0]+p.flat_b[16+l]; }
  }
  {
    f32x4 c0={0,0,0,0},c1={0,0,0,0};
    for(int kt=0;kt<2;kt++){
      s16x8 aE = packrow(&ego[kt*32 + q*8]);
      c0=MFMA(aE,BFR(T_VEGO+kt*2+0),c0); c1=MFMA(aE,BFR(T_VEGO+kt*2+1),c1);
    }
    if(l<16){ egh[l]=c0[0]+p.vr_bego[l]; egh[16+l]=c1[0]+p.vr_bego[16+l]; }
  }
  WF();
  // flat gelu; vh MFMA (ath | egh) -> vq raw
  if(l<32) zb[288+l]=0.25f*gelu_f(zb[288+l]);
  {
    s16x8 aY = *(const s16x8*)&ath[mm*YHS + q*8];
    s16x8 aE = packrow(&egh[q*8]);
    f32x4 c0={0,0,0,0},c1={0,0,0,0};
    c0=MFMA(aY,BFR(T_VH+0),c0); c1=MFMA(aY,BFR(T_VH+1),c1);
    c0=MFMA(aE,BFR(T_VH+2),c0); c1=MFMA(aE,BFR(T_VH+3),c1);
    #pragma unroll
    for(int r=0;r<4;r++){ int row=q*4+r;
      if(row<SLOTS){
        vq[row*ST+m]   =c0[r]+p.vr_bh[m];
        vq[row*ST+16+m]=c1[r]+p.vr_bh[16+m];
      }
    }
  }
  WF();
  // vr logits: gelu fused, dual-reduce, 3 passes
  for (int sp=0; sp<6; sp+=2){
    int sl = sp + (l>>5), i = l&31;
    bool act = sl < SLOTS;
    float g = act ? gelu_f(vq[sl*ST+i]) : 0.f;
    float v0 = g*p.vr_wl[i*2], v1 = g*p.vr_wl[i*2+1];
    red5_2(v0,v1);
    if(act && i==0){ lg[sl*2]=v0+p.vr_bl[0]; lg[sl*2+1]=v1+p.vr_bl[1]; }
  }
  WF();
  // vr softmax (2 rows, 8-lane groups)
  if (l<16){
    int s=l&7, hh=l>>3;
    bool keep=(s<5)&&(mk[s<5?s:0]!=0);
    float x= keep? lg[(s<5?s:0)*2+hh] : NEGB;
    float mx=x;
    mx=fmaxf(mx,__shfl_xor(mx,1,8)); mx=fmaxf(mx,__shfl_xor(mx,2,8)); mx=fmaxf(mx,__shfl_xor(mx,4,8));
    float e= keep? __expf(x-mx):0.f;
    float se=e;
    se+=__shfl_xor(se,1,8); se+=__shfl_xor(se,2,8); se+=__shfl_xor(se,4,8);
    if (s<5) a2[s*2+hh]= se>0.f? e/se:0.f;
  }
  WF();
  // v_r / v_u tail
  if (l<12){ int w = l/6, rem=l%6, hh=rem/3, d=rem%3;
    float a=0;
    for(int sl=0;sl<5;sl++) a += a2[sl*2+hh]*ru[sl*6 + w*3 + d];
    zb[320 + w*6 + hh*3 + d]=a; }
  WF();   // z[332] complete; U dead; U becomes z-phase overlay

  // convert own zb -> bf16 zbh
  {
    short* zbh = (short*)(W + OF_U + 300);
    for (int t=l;t<88;t+=64){
      s16x4 o;
      if (t<83){
        f32x4 v = *(const f32x4*)&zb[t*4];
        #pragma unroll
        for(int j=0;j<4;j++) o[j]=f2bf(v[j]);
      } else {
        #pragma unroll
        for(int j=0;j<4;j++) o[j]=0;
      }
      *(s16x4*)&zbh[t*4]=o;
    }
  }
  __syncthreads();   // cross-wave: all 4 tokens' zbh needed below

  // ---- fused z-phase (MFMA): GEMM1 K=352
  {
    f32x4 acc0 = {0.f,0.f,0.f,0.f}, acc1 = {0.f,0.f,0.f,0.f};
    const short* zbhM = (const short*)(pool + (m<4?m:0)*PW + OF_U + 300);
    for (int kt=0; kt<11; kt++){
      s16x8 af;
      if (m < 4) af = *(const s16x8*)&zbhM[kt*32 + q*8];
      else {
        #pragma unroll
        for (int j=0;j<8;j++) af[j]=0;
      }
      s16x8 b0 = wsv[(T_ZW1 + kt*8 + 2*wid  )*64 + l];
      s16x8 b1 = wsv[(T_ZW1 + kt*8 + 2*wid+1)*64 + l];
      acc0 = MFMA(af, b0, acc0);
      acc1 = MFMA(af, b1, acc1);
    }
    if (q == 0){
      int c0 = 2*wid*16 + m, c1 = (2*wid+1)*16 + m;
      float bb0 = p.z_b1[c0], bb1 = p.z_b1[c1];
      #pragma unroll
      for (int r=0;r<4;r++){
        pool[r*PW + OF_U + c0] = gelu_f(acc0[r] + bb0);   // h1
        pool[r*PW + OF_U + c1] = gelu_f(acc1[r] + bb1);
      }
    }
  }
  __syncthreads();
  // LN1 on own token's h1 -> h1h (bf16), dual-tree
  {
    float v0 = pool[wid*PW + OF_U + l], v1 = pool[wid*PW + OF_U + l+64];
    float sum = v0+v1, qq = v0*v0+v1*v1;
    for (int o=32;o>=1;o>>=1){ sum += __shfl_xor(sum,o,64); qq += __shfl_xor(qq,o,64); }
    float mu = sum*(1.f/128.f);
    float rs = rsqrtf(qq*(1.f/128.f)-mu*mu+1e-6f);
    short* h1h = (short*)(W + OF_U + 476);
    h1h[l]    = f2bf((v0-mu)*rs*p.z_ln1_s[l]   +p.z_ln1_b[l]);
    h1h[l+64] = f2bf((v1-mu)*rs*p.z_ln1_s[l+64]+p.z_ln1_b[l+64]);
  }
  __syncthreads();
  // GEMM2 K=128
  {
    f32x4 acc0 = {0.f,0.f,0.f,0.f}, acc1 = {0.f,0.f,0.f,0.f};
    const short* h1hM = (const short*)(pool + (m<4?m:0)*PW + OF_U + 476);
    for (int kt=0; kt<4; kt++){
      s16x8 af;
      if (m < 4) af = *(const s16x8*)&h1hM[kt*32 + q*8];
      else {
        #pragma unroll
        for (int j=0;j<8;j++) af[j]=0;
      }
      s16x8 b0 = wsv[(T_ZW2 + kt*8 + 2*wid  )*64 + l];
      s16x8 b1 = wsv[(T_ZW2 + kt*8 + 2*wid+1)*64 + l];
      acc0 = MFMA(af, b0, acc0);
      acc1 = MFMA(af, b1, acc1);
    }
    if (q == 0){
      int c0 = 2*wid*16 + m, c1 = (2*wid+1)*16 + m;
      float bb0 = p.z_b2[c0], bb1 = p.z_b2[c1];
      #pragma unroll
      for (int r=0;r<4;r++){
        pool[r*PW + OF_U + 128 + c0] = gelu_f(acc0[r] + bb0);   // h2
        pool[r*PW + OF_U + 128 + c1] = gelu_f(acc1[r] + bb1);
      }
    }
  }
  __syncthreads();
  // LN2 per wave + store (dual-tree)
  {
    float v0 = pool[wid*PW + OF_U + 128 + l], v1 = pool[wid*PW + OF_U + 128 + l+64];
    float sum = v0+v1, qq = v0*v0+v1*v1;
    for (int o=32;o>=1;o>>=1){ sum += __shfl_xor(sum,o,64); qq += __shfl_xor(qq,o,64); }
    float mu = sum*(1.f/128.f);
    float rs = rsqrtf(qq*(1.f/128.f)-mu*mu+1e-6f);
    float o0 = (v0-mu)*rs*p.z_ln2_s[l]   +p.z_ln2_b[l];
    float o1 = (v1-mu)*rs*p.z_ln2_s[l+64]+p.z_ln2_b[l+64];
    float* op = outp + (size_t)tok*128;
    op[l]    = o0;
    op[l+64] = o1;
  }
}

extern "C" void kernel_launch(void* const* d_in, const int* in_sizes, int n_in,
                              void* d_out, int out_size, void* d_ws, size_t ws_size,
                              hipStream_t stream) {
  (void)in_sizes; (void)n_in; (void)out_size; (void)ws_size;
  P p;
  const void** pp = (const void**)&p;
  for (int i=0;i<54;i++) pp[i] = d_in[i];
  short* wsb = (short*)d_ws;   // 184320 B needed
  k_prep<<<(T_TOT*512+255)/256, 256, 0, stream>>>(p, wsb);
  k_token<<<NTOK/WV, 256, 0, stream>>>(p, (float*)d_out, wsb);
}

// Round 5
// 1157.286 us; speedup vs baseline: 1.4192x; 1.0082x over previous
//
#include <hip/hip_runtime.h>
#include <hip/hip_bf16.h>

#define SLOTS 5
#define PER 15
#define EGO_DD 32
#define PAIR_DD 10
#define TER_DD 81
#define DX 198
#define ZDIM 332
#define NTOK (64*2048)
#define NEGB (-3.402823466e38f)
#define ST 36      // padded stride for [5][32] f32 slot arrays
#define HBST 68    // padded stride for [5][64] f32 ffn hidden
#define YHS 40     // padded stride (shorts) for bf16 [5][32]
#define HHS 72     // padded stride (shorts) for bf16 [5][64]

// ---- B-fragment tile table ----
#define T_EGO   0
#define T_PAIR  4
#define T_TER   6
#define T_INV   18
#define T_Q     20
#define T_K     22
#define T_V     24
#define T_O     26
#define T_W1    28
#define T_W2    32
#define T_APQ   36
#define T_APK   40
#define T_FLAT  42
#define T_VEGO  52
#define T_VH    56
#define T_ZW1   60
#define T_ZW2   148
#define T_TOT   180
#define WS_NEED (T_TOT*512*2)

// ---- per-wave LDS pool layout (floats), PW = 1332 (block ~21.5KB -> 7 blocks/CU) ----
#define PW 1332
#define OF_EGO 0      // egoh bf16[64] = 32 f
#define OF_TV  32     // tv f32 [5][ST] = 180 f
#define OF_YB  212    // yb f32 / ybh bf16 = 180 f
#define OF_U   392    // overlay region = 540 f
#define OF_AT  932    // at f32 scores/weights; ath bf16 (tail) = 100 f
#define OF_ZB  1032   // zbh bf16[352] = 176 f
#define OF_QEB 1208   // 32 f
#define OF_EGH 1240   // eghh bf16[32] = 16 f
#define OF_RU  1256   // 30 f
#define OF_SM  1286   // 44 f
// U overlays (disjoint lifetimes):
//   phase A: xb[198] @U+0, S raw ego/pair/ter [160] @U+200
//   phase B: qb@U+0, kb@U+180, vb@U+360 (each 180)
//   phase C: hb[5*68=340] @U+0, hbh bf16 @U+344 (180 f)
//   phase D: vq[180] @U+0
//   phase E (z): h1[128]@U+0, h2[128]@U+128, h1h bf16[128]@U+476 (64 f)

typedef float f32x4 __attribute__((ext_vector_type(4)));
typedef short s16x8 __attribute__((ext_vector_type(8)));
typedef short s16x4 __attribute__((ext_vector_type(4)));
#define MFMA(a,b,c) __builtin_amdgcn_mfma_f32_16x16x32_bf16(a,b,c,0,0,0)
// Intra-wave phase separator: compiler memory fence only (same-wave LDS is
// ordered in HW; cross-wave data only at the z-phase barriers).
#define WF() asm volatile("" ::: "memory")

struct P {
  const float *x,*w_ego,*b_ego,*w_pair,*b_pair,*w_ter,*b_ter,*w_invtok,*b_invtok,
    *ln1_s,*ln1_b,*wq,*bq,*wk,*bk,*wv,*bv,*wo,*bo,*ln2_s,*ln2_b,*w1,*b1,*w2,*b2,
    *sp_ln_s,*sp_ln_b,*sp_w,*sp_b,*sp_lt,*ap_wq,*ap_bq,*ap_wk,*ap_bk,*ap_we,*ap_be,
    *flat_w,*flat_b,*vr_wego,*vr_bego,*vr_ln_s,*vr_ln_b,*vr_wh,*vr_bh,*vr_wl,*vr_bl,
    *z_w1,*z_b1,*z_ln1_s,*z_ln1_b,*z_w2,*z_b2,*z_ln2_s,*z_ln2_b;
};

__device__ __forceinline__ short f2bf(float x){
  __hip_bfloat16 h = __float2bfloat16(x);
  return *reinterpret_cast<short*>(&h);
}
__device__ __forceinline__ float tanh_f(float x){
  float e = __expf(2.f*x);
  return 1.f - 2.f/(e+1.f);
}
__device__ __forceinline__ float gelu_f(float x){
  return 0.5f*x*(1.f+tanh_f(0.7978845608028654f*(x + 0.044715f*x*x*x)));
}
__device__ __forceinline__ s16x8 packrow(const float* r){
  s16x8 af;
  #pragma unroll
  for(int j=0;j<8;j++) af[j]=f2bf(r[j]);
  return af;
}
__device__ __forceinline__ s16x8 packrowb(const float* r, int k0, int K){
  s16x8 af;
  #pragma unroll
  for(int j=0;j<8;j++) af[j] = (k0+j<K) ? f2bf(r[k0+j]) : (short)0;
  return af;
}

// dual interleaved 32-lane reduce (two independent chains pipeline)
__device__ __forceinline__ void red5_2(float&a,float&b){
  a+=__shfl_xor(a,16,32); b+=__shfl_xor(b,16,32);
  a+=__shfl_xor(a,8,32);  b+=__shfl_xor(b,8,32);
  a+=__shfl_xor(a,4,32);  b+=__shfl_xor(b,4,32);
  a+=__shfl_xor(a,2,32);  b+=__shfl_xor(b,2,32);
  a+=__shfl_xor(a,1,32);  b+=__shfl_xor(b,1,32);
}
__device__ __forceinline__ float red5(float a){
  a+=__shfl_xor(a,16,32); a+=__shfl_xor(a,8,32); a+=__shfl_xor(a,4,32);
  a+=__shfl_xor(a,2,32);  a+=__shfl_xor(a,1,32);
  return a;
}

// LayerNorm (dual-tree) -> bf16 dst (stride YHS)
__device__ void ln5x32h(const float* src, short* dst, const float* Sc, const float* Bi, int l){
  for (int sp=0; sp<6; sp+=2){
    int sl = sp + (l>>5), i = l&31;
    bool act = sl < SLOTS;
    float v = act ? src[sl*ST+i] : 0.f;
    float s=v, ss=v*v;
    red5_2(s,ss);
    float mu=s*(1.f/32.f);
    float rstd=rsqrtf(ss*(1.f/32.f)-mu*mu+1e-6f);
    if(act) dst[sl*YHS+i]=f2bf((v-mu)*rstd*Sc[i]+Bi[i]);
  }
}
// fused sp+vr LN on the same src (same mu/rstd!): vr -> bf16 ath; sp scores -> scs
__device__ void ln5_spvr(const float* src, short* ath, float* scs,
    const float* sps, const float* spb, const float* vrs, const float* vrb,
    const float* spw, float spbias, int l){
  for (int sp=0; sp<6; sp+=2){
    int sl = sp + (l>>5), i = l&31;
    bool act = sl < SLOTS;
    float v = act ? src[sl*ST+i] : 0.f;
    float s=v, ss=v*v;
    red5_2(s,ss);
    float mu=s*(1.f/32.f);
    float rstd=rsqrtf(ss*(1.f/32.f)-mu*mu+1e-6f);
    float d=(v-mu)*rstd;
    if(act) ath[sl*YHS+i]=f2bf(d*vrs[i]+vrb[i]);
    float t=(d*sps[i]+spb[i])*spw[i];
    t=red5(t);
    if(act && i==0) scs[sl]=t+spbias;
  }
}

// pack all weights into bf16 B-fragments
__global__ __launch_bounds__(256) void k_prep(P p, short* __restrict__ ws){
  int idx = blockIdx.x*256 + threadIdx.x;
  if (idx >= T_TOT*512) return;
  int j = idx & 7, lane = (idx>>3)&63, tile = idx>>9;
  const float* src; int K,N,ntc,t0;
  if      (tile < T_PAIR){ src=p.w_ego;   K=32;  N=64;  ntc=4; t0=T_EGO; }
  else if (tile < T_TER ){ src=p.w_pair;  K=10;  N=32;  ntc=2; t0=T_PAIR; }
  else if (tile < T_INV ){ src=p.w_ter;   K=81;  N=64;  ntc=4; t0=T_TER; }
  else if (tile < T_Q   ){ src=p.w_invtok;K=10;  N=32;  ntc=2; t0=T_INV; }
  else if (tile < T_K   ){ src=p.wq;      K=32;  N=32;  ntc=2; t0=T_Q; }
  else if (tile < T_V   ){ src=p.wk;      K=32;  N=32;  ntc=2; t0=T_K; }
  else if (tile < T_O   ){ src=p.wv;      K=32;  N=32;  ntc=2; t0=T_V; }
  else if (tile < T_W1  ){ src=p.wo;      K=32;  N=32;  ntc=2; t0=T_O; }
  else if (tile < T_W2  ){ src=p.w1;      K=32;  N=64;  ntc=4; t0=T_W1; }
  else if (tile < T_APQ ){ src=p.w2;      K=64;  N=32;  ntc=2; t0=T_W2; }
  else if (tile < T_APK ){ src=p.ap_wq;   K=64;  N=32;  ntc=2; t0=T_APQ; }
  else if (tile < T_FLAT){ src=p.ap_wk;   K=32;  N=32;  ntc=2; t0=T_APK; }
  else if (tile < T_VEGO){ src=p.flat_w;  K=160; N=32;  ntc=2; t0=T_FLAT; }
  else if (tile < T_VH  ){ src=p.vr_wego; K=64;  N=32;  ntc=2; t0=T_VEGO; }
  else if (tile < T_ZW1 ){ src=p.vr_wh;   K=64;  N=32;  ntc=2; t0=T_VH; }
  else if (tile < T_ZW2 ){ src=p.z_w1;    K=ZDIM;N=128; ntc=8; t0=T_ZW1; }
  else                   { src=p.z_w2;    K=128; N=128; ntc=8; t0=T_ZW2; }
  int tl = tile - t0, ktI = tl/ntc, ntI = tl%ntc;
  int k = ktI*32 + ((lane>>4)<<3) + j, n = ntI*16 + (lane&15);
  float v = (k<K && n<N) ? src[k*N+n] : 0.f;
  ws[idx] = f2bf(v);
}

#define WV 4
__global__ __launch_bounds__(256) void k_token(P p, float* __restrict__ outp,
                                               const short* __restrict__ wsb) {
  __shared__ __align__(16) float pool[WV*PW];
  __shared__ int mkA[WV][5];
  __shared__ int mksA[WV][5];
  const s16x8* wsv = (const s16x8*)wsb;
  int wid = threadIdx.x >> 6, l = threadIdx.x & 63;
  float* W   = pool + wid*PW;
  short* egoh = (short*)(W + OF_EGO);     // bf16 gelu'd ego_e [64]
  float* tv  = W + OF_TV;
  float* yb  = W + OF_YB;                 // f32 view (ap raw scores)
  short* ybh = (short*)(W + OF_YB);       // bf16 view (LN1/LN2/attn-y)
  float* U   = W + OF_U;
  float* at  = W + OF_AT;
  short* ath = (short*)(W + OF_AT);       // vr-LN bf16 (tail reuse)
  short* zbh = (short*)(W + OF_ZB);       // z vector, bf16 [352]
  float* qeb = W + OF_QEB;
  short* eghh = (short*)(W + OF_EGH);     // bf16 vr ego hidden [32]
  float* ru  = W + OF_RU;
  float* sm  = W + OF_SM;
  float* scs = sm+0; float* wts = sm+5; float* alp = sm+10; float* lg = sm+16;
  float* a2 = sm+26; float* aps = sm+36;
  int* mk  = mkA[wid];
  int* mks = mksA[wid];
  // U overlays
  float* xb = U;                 // phase A input
  float* S  = U + 200;           // phase A raw ego/pair/ter [160]
  float* qb = U;  float* kb = U+180;  float* vb = U+360;   // phase B
  float* hb = U;                                            // phase C (f32 raw)
  short* hbh = (short*)(U + 344);                            // phase C (bf16 gelu'd)
  float* vq = U;                 // tail: vh raw output
  long tok = (long)blockIdx.x*WV + wid;
  int m = l & 15, q = l >> 4;
  int mm = m < 5 ? m : 4;
#define BFR(tile) wsv[(tile)*64 + l]

  // x load: 198 f32 = 99 float2
  {
    const float2* xr2 = (const float2*)(p.x + (size_t)tok*DX);
    float2* xb2 = (float2*)xb;
    for (int i=l;i<99;i+=64) xb2[i] = xr2[i];
  }
  WF();

  // mask from r = nbr[...,0:3]
  if (l < SLOTS) { int nb = EGO_DD + l*PER;
    mk[l] = (fabsf(xb[nb])>1e-6f || fabsf(xb[nb+1])>1e-6f || fabsf(xb[nb+2])>1e-6f) ? 1 : 0; }
  // save r/u for final z-tail (xb will be overwritten)
  if (l < 30){ int sl=l/6, d=l%6; ru[l] = xb[EGO_DD + sl*PER + d]; }
  WF();
  int nmask = mk[0]+mk[1]+mk[2]+mk[3]+mk[4];
  bool hasany = nmask>0;
  if (l < SLOTS) mks[l] = hasany ? mk[l] : (l==0 ? 1 : 0);

  // ---- ego/pair/ter (M=1) raw+bias -> S[0:160]
  {
    s16x8 aE = packrow(&xb[q*8]);
    s16x8 aP = packrowb(&xb[107], q*8, 10);
    f32x4 e0={0,0,0,0},e1={0,0,0,0},e2={0,0,0,0},e3={0,0,0,0};
    e0=MFMA(aE,BFR(T_EGO+0),e0); e1=MFMA(aE,BFR(T_EGO+1),e1);
    e2=MFMA(aE,BFR(T_EGO+2),e2); e3=MFMA(aE,BFR(T_EGO+3),e3);
    f32x4 p0={0,0,0,0},p1={0,0,0,0};
    p0=MFMA(aP,BFR(T_PAIR+0),p0); p1=MFMA(aP,BFR(T_PAIR+1),p1);
    if (l<16){
      S[l]    = e0[0]+p.b_ego[l];    S[16+l] = e1[0]+p.b_ego[16+l];
      S[32+l] = e2[0]+p.b_ego[32+l]; S[48+l] = e3[0]+p.b_ego[48+l];
      S[64+l] = p0[0]+p.b_pair[l];   S[80+l] = p1[0]+p.b_pair[16+l];
    }
  }
  {
    f32x4 t0={0,0,0,0},t1={0,0,0,0},t2={0,0,0,0},t3={0,0,0,0};
    for(int kt=0;kt<3;kt++){
      s16x8 aT = packrowb(&xb[117], kt*32+q*8, 81);
      t0=MFMA(aT,BFR(T_TER+kt*4+0),t0); t1=MFMA(aT,BFR(T_TER+kt*4+1),t1);
      t2=MFMA(aT,BFR(T_TER+kt*4+2),t2); t3=MFMA(aT,BFR(T_TER+kt*4+3),t3);
    }
    if (l<16){
      S[96+l] = t0[0]+p.b_ter[l];    S[112+l]= t1[0]+p.b_ter[16+l];
      S[128+l]= t2[0]+p.b_ter[32+l]; S[144+l]= t3[0]+p.b_ter[48+l];
    }
  }
  // ---- invtok (M=16/5) raw+bias -> tv
  {
    int nb = EGO_DD + mm*PER;
    float a0=xb[nb+6],a1=xb[nb+7],a2v=xb[nb+8];
    float nrm = sqrtf(a0*a0+a1*a1+a2v*a2v);
    s16x8 af;
    #pragma unroll
    for(int j=0;j<8;j++){
      int k=q*8+j; float v;
      if(k<6) v=xb[nb+9+k];
      else if(k<9) v=xb[nb+k];
      else if(k==9) v=nrm;
      else v=0.f;
      af[j]=f2bf(v);
    }
    f32x4 c0={0,0,0,0},c1={0,0,0,0};
    c0=MFMA(af,BFR(T_INV+0),c0); c1=MFMA(af,BFR(T_INV+1),c1);
    #pragma unroll
    for(int r=0;r<4;r++){ int row=q*4+r;
      if(row<SLOTS){
        tv[row*ST+m]    = c0[r]+p.b_invtok[m];
        tv[row*ST+16+m] = c1[r]+p.b_invtok[16+m];
      }
    }
  }
  WF();
  // gelu(S) -> zbh[0:160] bf16 (+ egoh copy of first 64)
  if (l<40){
    f32x4 v = *(f32x4*)&S[l*4];
    s16x4 o;
    #pragma unroll
    for(int j=0;j<4;j++) o[j]=f2bf(gelu_f(v[j]));
    *(s16x4*)&zbh[l*4]=o;
    if (l<16) *(s16x4*)&egoh[l*4]=o;
  }
  // tv gelu (vec4, masked)
  if (l<40){
    int sl=l>>3, i4=(l&7)*4;
    f32x4 v = *(f32x4*)&tv[sl*ST+i4];
    if (mk[sl]){
      #pragma unroll
      for(int j=0;j<4;j++) v[j]=gelu_f(v[j]);
    } else { v = (f32x4){0.f,0.f,0.f,0.f}; }
    *(f32x4*)&tv[sl*ST+i4]=v;
  }
  WF();   // xb/S dead from here; U becomes qb/kb/vb

  // ---- LN1 -> bf16 ybh -> qkv
  ln5x32h(tv, ybh, p.ln1_s, p.ln1_b, l);
  WF();
  {
    s16x8 aY = *(const s16x8*)&ybh[mm*YHS + q*8];
    f32x4 q0={0,0,0,0},q1={0,0,0,0},k0v={0,0,0,0},k1v={0,0,0,0},v0={0,0,0,0},v1={0,0,0,0};
    q0=MFMA(aY,BFR(T_Q+0),q0);   q1=MFMA(aY,BFR(T_Q+1),q1);
    k0v=MFMA(aY,BFR(T_K+0),k0v); k1v=MFMA(aY,BFR(T_K+1),k1v);
    v0=MFMA(aY,BFR(T_V+0),v0);   v1=MFMA(aY,BFR(T_V+1),v1);
    #pragma unroll
    for(int r=0;r<4;r++){ int row=q*4+r;
      if(row<SLOTS){
        qb[row*ST+m]=q0[r]+p.bq[m];     qb[row*ST+16+m]=q1[r]+p.bq[16+m];
        kb[row*ST+m]=k0v[r]+p.bk[m];    kb[row*ST+16+m]=k1v[r]+p.bk[16+m];
        vb[row*ST+m]=v0[r]+p.bv[m];     vb[row*ST+16+m]=v1[r]+p.bv[16+m];
      }
    }
  }
  WF();
  // attention scores
  for (int t=l; t<100; t+=64){
    int h=t/25, r2=t%25, qs=r2/5, ks=r2%5;
    const f32x4* qp=(const f32x4*)&qb[qs*ST+h*8];
    const f32x4* kp=(const f32x4*)&kb[ks*ST+h*8];
    f32x4 q0=qp[0], q1=qp[1], k0=kp[0], k1=kp[1];
    float d8 = q0[0]*k0[0]+q0[1]*k0[1]+q0[2]*k0[2]+q0[3]*k0[3]
             + q1[0]*k1[0]+q1[1]*k1[1]+q1[2]*k1[2]+q1[3]*k1[3];
    at[t] = (mks[qs]&&mks[ks]) ? d8*0.35355339059327373f : NEGB;
  }
  WF();
  // softmax over ks (20 lanes)
  if (l<20){
    float e[5]; float mx=NEGB, se=0.f;
    #pragma unroll
    for(int ks=0;ks<5;ks++) mx=fmaxf(mx, at[l*5+ks]);
    #pragma unroll
    for(int ks=0;ks<5;ks++){ e[ks]=__expf(at[l*5+ks]-mx); se+=e[ks]; }
    float inv=1.f/se;
    #pragma unroll
    for(int ks=0;ks<5;ks++) at[l*5+ks]=e[ks]*inv;
  }
  WF();
  // attn @ v -> ybh bf16
  if (l<40){
    int sl=l>>3, i4=(l&7)*4, h=i4>>3, d=i4&7;
    f32x4 acc={0.f,0.f,0.f,0.f};
    #pragma unroll
    for(int ks=0;ks<5;ks++){
      float w = at[(h*5+sl)*5+ks];
      f32x4 vv = *(const f32x4*)&vb[ks*ST+h*8+d];
      acc += vv*w;
    }
    s16x4 o;
    #pragma unroll
    for(int j=0;j<4;j++) o[j]=f2bf(acc[j]);
    *(s16x4*)&ybh[sl*YHS+i4]=o;
  }
  WF();
  // wo + residual (zero_masked)
  {
    s16x8 aY = *(const s16x8*)&ybh[mm*YHS + q*8];
    f32x4 c0={0,0,0,0},c1={0,0,0,0};
    c0=MFMA(aY,BFR(T_O+0),c0); c1=MFMA(aY,BFR(T_O+1),c1);
    #pragma unroll
    for(int r=0;r<4;r++){ int row=q*4+r;
      if(row<SLOTS && mk[row]){
        tv[row*ST+m]    += c0[r]+p.bo[m];
        tv[row*ST+16+m] += c1[r]+p.bo[16+m];
      }
    }
  }
  WF();
  // LN2 + FFN (qb/kb/vb dead; U becomes hb/hbh)
  ln5x32h(tv, ybh, p.ln2_s, p.ln2_b, l);
  WF();
  {
    s16x8 aY = *(const s16x8*)&ybh[mm*YHS + q*8];
    f32x4 c0={0,0,0,0},c1={0,0,0,0},c2={0,0,0,0},c3={0,0,0,0};
    c0=MFMA(aY,BFR(T_W1+0),c0); c1=MFMA(aY,BFR(T_W1+1),c1);
    c2=MFMA(aY,BFR(T_W1+2),c2); c3=MFMA(aY,BFR(T_W1+3),c3);
    #pragma unroll
    for(int r=0;r<4;r++){ int row=q*4+r;
      if(row<SLOTS){
        hb[row*HBST+m]   =c0[r]+p.b1[m];
        hb[row*HBST+16+m]=c1[r]+p.b1[16+m];
        hb[row*HBST+32+m]=c2[r]+p.b1[32+m];
        hb[row*HBST+48+m]=c3[r]+p.b1[48+m];
      }
    }
  }
  WF();
  for (int t=l;t<80;t+=64){
    int sl=t>>4, j4=(t&15)*4;
    f32x4 v = *(f32x4*)&hb[sl*HBST+j4];
    s16x4 o;
    #pragma unroll
    for(int j=0;j<4;j++) o[j]=f2bf(gelu_f(v[j]));
    *(s16x4*)&hbh[sl*HHS+j4]=o;
  }
  WF();
  {
    f32x4 c0={0,0,0,0},c1={0,0,0,0};
    for(int kt=0;kt<2;kt++){
      s16x8 aH = *(const s16x8*)&hbh[mm*HHS + kt*32 + q*8];
      c0=MFMA(aH,BFR(T_W2+kt*2+0),c0); c1=MFMA(aH,BFR(T_W2+kt*2+1),c1);
    }
    #pragma unroll
    for(int r=0;r<4;r++){ int row=q*4+r;
      if(row<SLOTS){
        float n0 = mk[row] ? tv[row*ST+m]+c0[r]+p.b2[m] : 0.f;
        float n1 = mk[row] ? tv[row*ST+16+m]+c1[r]+p.b2[16+m] : 0.f;
        tv[row*ST+m]=n0; tv[row*ST+16+m]=n1;
      }
    }
  }
  WF();   // tv final

  // pools: mean / max -> zbh bf16
  if (l<32){
    float v0=tv[l],v1=tv[ST+l],v2=tv[2*ST+l],v3=tv[3*ST+l],v4=tv[4*ST+l];
    int cnt = nmask>0?nmask:1;
    zbh[160+l]=f2bf((v0+v1+v2+v3+v4)/(float)cnt);
    float mx=-1e9f;
    if(mk[0])mx=fmaxf(mx,v0); if(mk[1])mx=fmaxf(mx,v1); if(mk[2])mx=fmaxf(mx,v2);
    if(mk[3])mx=fmaxf(mx,v3); if(mk[4])mx=fmaxf(mx,v4);
    zbh[192+l]= f2bf(hasany ? mx : 0.f);
  }
  // fused sp+vr LN: vr-LN -> ath bf16; sp scores -> scs
  ln5_spvr(tv, ath, scs, p.sp_ln_s, p.sp_ln_b, p.vr_ln_s, p.vr_ln_b,
           p.sp_w, p.sp_b[0], l);
  WF();
  // sp softmax (8-lane parallel)
  if (l<8){
    float temp = log1pf(expf(p.sp_lt[0])) + 0.001f;
    bool keep=(l<5)&&(mk[l]!=0);
    float x= keep? temp*scs[l] : NEGB;
    float mx=x;
    mx=fmaxf(mx,__shfl_xor(mx,1,8)); mx=fmaxf(mx,__shfl_xor(mx,2,8)); mx=fmaxf(mx,__shfl_xor(mx,4,8));
    float e= keep? __expf(x-mx):0.f;
    float se=e;
    se+=__shfl_xor(se,1,8); se+=__shfl_xor(se,2,8); se+=__shfl_xor(se,4,8);
    if (l<5) wts[l]= se>0.f? e/se:0.f;
  }
  WF();
  // sp wsum -> zbh
  if (l<32){ float a=0;
    for(int sl=0;sl<5;sl++) a += wts[sl]*tv[sl*ST+l];
    zbh[224+l]=f2bf(a); }
  // ap_wq (M=1, K=64) from egoh -> qeb
  {
    f32x4 c0={0,0,0,0},c1={0,0,0,0};
    for(int kt=0;kt<2;kt++){
      s16x8 aE = *(const s16x8*)&egoh[kt*32 + q*8];
      c0=MFMA(aE,BFR(T_APQ+kt*2+0),c0); c1=MFMA(aE,BFR(T_APQ+kt*2+1),c1);
    }
    if(l<16){ qeb[l]=c0[0]+p.ap_bq[l]; qeb[16+l]=c1[0]+p.ap_bq[16+l]; }
  }
  WF();
  // ap_wk + qeb -> yb (raw, pre-tanh)
  {
    s16x8 aT = packrow(&tv[mm*ST + q*8]);
    f32x4 c0={0,0,0,0},c1={0,0,0,0};
    c0=MFMA(aT,BFR(T_APK+0),c0); c1=MFMA(aT,BFR(T_APK+1),c1);
    #pragma unroll
    for(int r=0;r<4;r++){ int row=q*4+r;
      if(row<SLOTS){
        yb[row*ST+m]   =c0[r]+p.ap_bk[m]+qeb[m];
        yb[row*ST+16+m]=c1[r]+p.ap_bk[16+m]+qeb[16+m];
      }
    }
  }
  WF();
  // ap score: tanh fused into the reduce
  for (int sp=0; sp<6; sp+=2){
    int sl = sp + (l>>5), i = l&31;
    float v = (sl<SLOTS) ? tanh_f(yb[sl*ST+i])*p.ap_we[i] : 0.f;
    v=red5(v);
    if (sl<SLOTS && i==0) aps[sl]=v+p.ap_be[0];
  }
  WF();
  // ap softmax (8-lane parallel)
  if (l<8){
    bool keep=(l<5)&&(mk[l]!=0);
    float x= keep? aps[l] : NEGB;
    float mx=x;
    mx=fmaxf(mx,__shfl_xor(mx,1,8)); mx=fmaxf(mx,__shfl_xor(mx,2,8)); mx=fmaxf(mx,__shfl_xor(mx,4,8));
    float e= keep? __expf(x-mx):0.f;
    float se=e;
    se+=__shfl_xor(se,1,8); se+=__shfl_xor(se,2,8); se+=__shfl_xor(se,4,8);
    if (l<5) alp[l]= se>0.f? e/se:0.f;
  }
  WF();
  // ap wsum -> zbh; flat (gelu fused in epilogue); vego -> eghh bf16
  if (l<32){ float a=0;
    for(int sl=0;sl<5;sl++) a += alp[sl]*tv[sl*ST+l];
    zbh[256+l]=f2bf(a); }
  {
    f32x4 c0={0,0,0,0},c1={0,0,0,0};
    for(int kt=0;kt<5;kt++){
      s16x8 aF = packrow(&tv[kt*ST + q*8]);
      c0=MFMA(aF,BFR(T_FLAT+kt*2+0),c0); c1=MFMA(aF,BFR(T_FLAT+kt*2+1),c1);
    }
    if(l<16){
      zbh[288+l]=f2bf(0.25f*gelu_f(c0[0]+p.flat_b[l]));
      zbh[304+l]=f2bf(0.25f*gelu_f(c1[0]+p.flat_b[16+l]));
    }
  }
  {
    f32x4 c0={0,0,0,0},c1={0,0,0,0};
    for(int kt=0;kt<2;kt++){
      s16x8 aE = *(const s16x8*)&egoh[kt*32 + q*8];
      c0=MFMA(aE,BFR(T_VEGO+kt*2+0),c0); c1=MFMA(aE,BFR(T_VEGO+kt*2+1),c1);
    }
    if(l<16){ eghh[l]=f2bf(c0[0]+p.vr_bego[l]); eghh[16+l]=f2bf(c1[0]+p.vr_bego[16+l]); }
  }
  WF();
  // vh MFMA (ath | eghh) -> vq raw
  {
    s16x8 aY = *(const s16x8*)&ath[mm*YHS + q*8];
    s16x8 aE = *(const s16x8*)&eghh[q*8];
    f32x4 c0={0,0,0,0},c1={0,0,0,0};
    c0=MFMA(aY,BFR(T_VH+0),c0); c1=MFMA(aY,BFR(T_VH+1),c1);
    c0=MFMA(aE,BFR(T_VH+2),c0); c1=MFMA(aE,BFR(T_VH+3),c1);
    #pragma unroll
    for(int r=0;r<4;r++){ int row=q*4+r;
      if(row<SLOTS){
        vq[row*ST+m]   =c0[r]+p.vr_bh[m];
        vq[row*ST+16+m]=c1[r]+p.vr_bh[16+m];
      }
    }
  }
  WF();
  // vr logits: gelu fused, dual-reduce, 3 passes
  for (int sp=0; sp<6; sp+=2){
    int sl = sp + (l>>5), i = l&31;
    bool act = sl < SLOTS;
    float g = act ? gelu_f(vq[sl*ST+i]) : 0.f;
    float v0 = g*p.vr_wl[i*2], v1 = g*p.vr_wl[i*2+1];
    red5_2(v0,v1);
    if(act && i==0){ lg[sl*2]=v0+p.vr_bl[0]; lg[sl*2+1]=v1+p.vr_bl[1]; }
  }
  WF();
  // vr softmax (2 rows, 8-lane groups)
  if (l<16){
    int s=l&7, hh=l>>3;
    bool keep=(s<5)&&(mk[s<5?s:0]!=0);
    float x= keep? lg[(s<5?s:0)*2+hh] : NEGB;
    float mx=x;
    mx=fmaxf(mx,__shfl_xor(mx,1,8)); mx=fmaxf(mx,__shfl_xor(mx,2,8)); mx=fmaxf(mx,__shfl_xor(mx,4,8));
    float e= keep? __expf(x-mx):0.f;
    float se=e;
    se+=__shfl_xor(se,1,8); se+=__shfl_xor(se,2,8); se+=__shfl_xor(se,4,8);
    if (s<5) a2[s*2+hh]= se>0.f? e/se:0.f;
  }
  WF();
  // v_r / v_u tail -> zbh; zero pad 332..351
  if (l<12){ int w = l/6, rem=l%6, hh=rem/3, d=rem%3;
    float a=0;
    for(int sl=0;sl<5;sl++) a += a2[sl*2+hh]*ru[sl*6 + w*3 + d];
    zbh[320 + w*6 + hh*3 + d]=f2bf(a); }
  else if (l<32) zbh[320+l]=0;
  __syncthreads();   // cross-wave: all 4 tokens' zbh needed below

  // ---- fused z-phase (MFMA): GEMM1 K=352
  {
    f32x4 acc0 = {0.f,0.f,0.f,0.f}, acc1 = {0.f,0.f,0.f,0.f};
    const short* zbhM = (const short*)(pool + (m<4?m:0)*PW + OF_ZB);
    for (int kt=0; kt<11; kt++){
      s16x8 af;
      if (m < 4) af = *(const s16x8*)&zbhM[kt*32 + q*8];
      else {
        #pragma unroll
        for (int j=0;j<8;j++) af[j]=0;
      }
      s16x8 b0 = wsv[(T_ZW1 + kt*8 + 2*wid  )*64 + l];
      s16x8 b1 = wsv[(T_ZW1 + kt*8 + 2*wid+1)*64 + l];
      acc0 = MFMA(af, b0, acc0);
      acc1 = MFMA(af, b1, acc1);
    }
    if (q == 0){
      int c0 = 2*wid*16 + m, c1 = (2*wid+1)*16 + m;
      float bb0 = p.z_b1[c0], bb1 = p.z_b1[c1];
      #pragma unroll
      for (int r=0;r<4;r++){
        pool[r*PW + OF_U + c0] = gelu_f(acc0[r] + bb0);   // h1
        pool[r*PW + OF_U + c1] = gelu_f(acc1[r] + bb1);
      }
    }
  }
  __syncthreads();
  // LN1 on own token's h1 -> h1h (bf16), dual-tree
  {
    float v0 = pool[wid*PW + OF_U + l], v1 = pool[wid*PW + OF_U + l+64];
    float sum = v0+v1, qq = v0*v0+v1*v1;
    for (int o=32;o>=1;o>>=1){ sum += __shfl_xor(sum,o,64); qq += __shfl_xor(qq,o,64); }
    float mu = sum*(1.f/128.f);
    float rs = rsqrtf(qq*(1.f/128.f)-mu*mu+1e-6f);
    short* h1h = (short*)(W + OF_U + 476);
    h1h[l]    = f2bf((v0-mu)*rs*p.z_ln1_s[l]   +p.z_ln1_b[l]);
    h1h[l+64] = f2bf((v1-mu)*rs*p.z_ln1_s[l+64]+p.z_ln1_b[l+64]);
  }
  __syncthreads();
  // GEMM2 K=128
  {
    f32x4 acc0 = {0.f,0.f,0.f,0.f}, acc1 = {0.f,0.f,0.f,0.f};
    const short* h1hM = (const short*)(pool + (m<4?m:0)*PW + OF_U + 476);
    for (int kt=0; kt<4; kt++){
      s16x8 af;
      if (m < 4) af = *(const s16x8*)&h1hM[kt*32 + q*8];
      else {
        #pragma unroll
        for (int j=0;j<8;j++) af[j]=0;
      }
      s16x8 b0 = wsv[(T_ZW2 + kt*8 + 2*wid  )*64 + l];
      s16x8 b1 = wsv[(T_ZW2 + kt*8 + 2*wid+1)*64 + l];
      acc0 = MFMA(af, b0, acc0);
      acc1 = MFMA(af, b1, acc1);
    }
    if (q == 0){
      int c0 = 2*wid*16 + m, c1 = (2*wid+1)*16 + m;
      float bb0 = p.z_b2[c0], bb1 = p.z_b2[c1];
      #pragma unroll
      for (int r=0;r<4;r++){
        pool[r*PW + OF_U + 128 + c0] = gelu_f(acc0[r] + bb0);   // h2
        pool[r*PW + OF_U + 128 + c1] = gelu_f(acc1[r] + bb1);
      }
    }
  }
  __syncthreads();
  // LN2 per wave + store (dual-tree)
  {
    float v0 = pool[wid*PW + OF_U + 128 + l], v1 = pool[wid*PW + OF_U + 128 + l+64];
    float sum = v0+v1, qq = v0*v0+v1*v1;
    for (int o=32;o>=1;o>>=1){ sum += __shfl_xor(sum,o,64); qq += __shfl_xor(qq,o,64); }
    float mu = sum*(1.f/128.f);
    float rs = rsqrtf(qq*(1.f/128.f)-mu*mu+1e-6f);
    float o0 = (v0-mu)*rs*p.z_ln2_s[l]   +p.z_ln2_b[l];
    float o1 = (v1-mu)*rs*p.z_ln2_s[l+64]+p.z_ln2_b[l+64];
    float* op = outp + (size_t)tok*128;
    op[l]    = o0;
    op[l+64] = o1;
  }
}

extern "C" void kernel_launch(void* const* d_in, const int* in_sizes, int n_in,
                              void* d_out, int out_size, void* d_ws, size_t ws_size,
                              hipStream_t stream) {
  (void)in_sizes; (void)n_in; (void)out_size; (void)ws_size;
  P p;
  const void** pp = (const void**)&p;
  for (int i=0;i<54;i++) pp[i] = d_in[i];
  short* wsb = (short*)d_ws;   // 184320 B needed
  k_prep<<<(T_TOT*512+255)/256, 256, 0, stream>>>(p, wsb);
  k_token<<<NTOK/WV, 256, 0, stream>>>(p, (float*)d_out, wsb);
}

// Round 6
// 1135.995 us; speedup vs baseline: 1.4458x; 1.0187x over previous
//
#include <hip/hip_runtime.h>
#include <hip/hip_bf16.h>

#define SLOTS 5
#define PER 15
#define EGO_DD 32
#define PAIR_DD 10
#define TER_DD 81
#define DX 198
#define ZDIM 332
#define NTOK (64*2048)
#define NEGB (-3.402823466e38f)
#define ST 36      // padded stride for [5][32] f32 slot arrays
#define HBST 68    // padded stride for [5][64] f32 ffn hidden
#define YHS 40     // padded stride (shorts) for bf16 [5][32]
#define HHS 72     // padded stride (shorts) for bf16 [5][64]

// ---- B-fragment tile table ----
#define T_EGO   0
#define T_PAIR  4
#define T_TER   6
#define T_INV   18
#define T_Q     20
#define T_K     22
#define T_V     24
#define T_O     26
#define T_W1    28
#define T_W2    32
#define T_APQ   36
#define T_APK   40
#define T_FLAT  42
#define T_VEGO  52
#define T_VH    56
#define T_ZW1   60
#define T_ZW2   148
#define T_TOT   180
#define WS_NEED (T_TOT*512*2)

// ---- per-wave LDS pool layout (floats), PW = 1332 ----
#define PW 1332
#define OF_EGO 0      // egoh bf16[64] = 32 f
#define OF_TV  32     // tv f32 [5][ST] = 180 f
#define OF_YB  212    // yb f32 / ybh bf16 = 180 f
#define OF_U   392    // overlay region = 540 f
#define OF_AT  932    // at f32 scores/weights; ath bf16 (tail) = 100 f
#define OF_ZB  1032   // zbh bf16[352] = 176 f
#define OF_QEB 1208   // 32 f
#define OF_EGH 1240   // eghh bf16[32] = 16 f
#define OF_RU  1256   // 30 f
#define OF_SM  1286   // 44 f

typedef float f32x4 __attribute__((ext_vector_type(4)));
typedef short s16x8 __attribute__((ext_vector_type(8)));
typedef short s16x4 __attribute__((ext_vector_type(4)));
#define MFMA(a,b,c) __builtin_amdgcn_mfma_f32_16x16x32_bf16(a,b,c,0,0,0)
// Intra-wave phase separator: compiler memory fence only (same-wave LDS is
// ordered in HW; cross-wave data only at the z-phase barriers).
#define WF() asm volatile("" ::: "memory")

struct P {
  const float *x,*w_ego,*b_ego,*w_pair,*b_pair,*w_ter,*b_ter,*w_invtok,*b_invtok,
    *ln1_s,*ln1_b,*wq,*bq,*wk,*bk,*wv,*bv,*wo,*bo,*ln2_s,*ln2_b,*w1,*b1,*w2,*b2,
    *sp_ln_s,*sp_ln_b,*sp_w,*sp_b,*sp_lt,*ap_wq,*ap_bq,*ap_wk,*ap_bk,*ap_we,*ap_be,
    *flat_w,*flat_b,*vr_wego,*vr_bego,*vr_ln_s,*vr_ln_b,*vr_wh,*vr_bh,*vr_wl,*vr_bl,
    *z_w1,*z_b1,*z_ln1_s,*z_ln1_b,*z_w2,*z_b2,*z_ln2_s,*z_ln2_b;
};

__device__ __forceinline__ short f2bf(float x){
  __hip_bfloat16 h = __float2bfloat16(x);
  return *reinterpret_cast<short*>(&h);
}
__device__ __forceinline__ float tanh_f(float x){
  float e = __expf(2.f*x);
  return 1.f - 2.f/(e+1.f);
}
__device__ __forceinline__ float gelu_f(float x){
  return 0.5f*x*(1.f+tanh_f(0.7978845608028654f*(x + 0.044715f*x*x*x)));
}
__device__ __forceinline__ s16x8 packrow(const float* r){
  s16x8 af;
  #pragma unroll
  for(int j=0;j<8;j++) af[j]=f2bf(r[j]);
  return af;
}
__device__ __forceinline__ s16x8 packrowb(const float* r, int k0, int K){
  s16x8 af;
  #pragma unroll
  for(int j=0;j<8;j++) af[j] = (k0+j<K) ? f2bf(r[k0+j]) : (short)0;
  return af;
}

// dual interleaved 32-lane reduce (two independent chains pipeline)
__device__ __forceinline__ void red5_2(float&a,float&b){
  a+=__shfl_xor(a,16,32); b+=__shfl_xor(b,16,32);
  a+=__shfl_xor(a,8,32);  b+=__shfl_xor(b,8,32);
  a+=__shfl_xor(a,4,32);  b+=__shfl_xor(b,4,32);
  a+=__shfl_xor(a,2,32);  b+=__shfl_xor(b,2,32);
  a+=__shfl_xor(a,1,32);  b+=__shfl_xor(b,1,32);
}
__device__ __forceinline__ float red5(float a){
  a+=__shfl_xor(a,16,32); a+=__shfl_xor(a,8,32); a+=__shfl_xor(a,4,32);
  a+=__shfl_xor(a,2,32);  a+=__shfl_xor(a,1,32);
  return a;
}

// LayerNorm (dual-tree) -> bf16 dst (stride YHS)
__device__ void ln5x32h(const float* src, short* dst, const float* Sc, const float* Bi, int l){
  for (int sp=0; sp<6; sp+=2){
    int sl = sp + (l>>5), i = l&31;
    bool act = sl < SLOTS;
    float v = act ? src[sl*ST+i] : 0.f;
    float s=v, ss=v*v;
    red5_2(s,ss);
    float mu=s*(1.f/32.f);
    float rstd=rsqrtf(ss*(1.f/32.f)-mu*mu+1e-6f);
    if(act) dst[sl*YHS+i]=f2bf((v-mu)*rstd*Sc[i]+Bi[i]);
  }
}
// fused sp+vr LN on the same src (same mu/rstd!): vr -> bf16 ath; sp scores -> scs
__device__ void ln5_spvr(const float* src, short* ath, float* scs,
    const float* sps, const float* spb, const float* vrs, const float* vrb,
    const float* spw, float spbias, int l){
  for (int sp=0; sp<6; sp+=2){
    int sl = sp + (l>>5), i = l&31;
    bool act = sl < SLOTS;
    float v = act ? src[sl*ST+i] : 0.f;
    float s=v, ss=v*v;
    red5_2(s,ss);
    float mu=s*(1.f/32.f);
    float rstd=rsqrtf(ss*(1.f/32.f)-mu*mu+1e-6f);
    float d=(v-mu)*rstd;
    if(act) ath[sl*YHS+i]=f2bf(d*vrs[i]+vrb[i]);
    float t=(d*sps[i]+spb[i])*spw[i];
    t=red5(t);
    if(act && i==0) scs[sl]=t+spbias;
  }
}

// pack all weights into bf16 B-fragments
__global__ __launch_bounds__(256) void k_prep(P p, short* __restrict__ ws){
  int idx = blockIdx.x*256 + threadIdx.x;
  if (idx >= T_TOT*512) return;
  int j = idx & 7, lane = (idx>>3)&63, tile = idx>>9;
  const float* src; int K,N,ntc,t0;
  if      (tile < T_PAIR){ src=p.w_ego;   K=32;  N=64;  ntc=4; t0=T_EGO; }
  else if (tile < T_TER ){ src=p.w_pair;  K=10;  N=32;  ntc=2; t0=T_PAIR; }
  else if (tile < T_INV ){ src=p.w_ter;   K=81;  N=64;  ntc=4; t0=T_TER; }
  else if (tile < T_Q   ){ src=p.w_invtok;K=10;  N=32;  ntc=2; t0=T_INV; }
  else if (tile < T_K   ){ src=p.wq;      K=32;  N=32;  ntc=2; t0=T_Q; }
  else if (tile < T_V   ){ src=p.wk;      K=32;  N=32;  ntc=2; t0=T_K; }
  else if (tile < T_O   ){ src=p.wv;      K=32;  N=32;  ntc=2; t0=T_V; }
  else if (tile < T_W1  ){ src=p.wo;      K=32;  N=32;  ntc=2; t0=T_O; }
  else if (tile < T_W2  ){ src=p.w1;      K=32;  N=64;  ntc=4; t0=T_W1; }
  else if (tile < T_APQ ){ src=p.w2;      K=64;  N=32;  ntc=2; t0=T_W2; }
  else if (tile < T_APK ){ src=p.ap_wq;   K=64;  N=32;  ntc=2; t0=T_APQ; }
  else if (tile < T_FLAT){ src=p.ap_wk;   K=32;  N=32;  ntc=2; t0=T_APK; }
  else if (tile < T_VEGO){ src=p.flat_w;  K=160; N=32;  ntc=2; t0=T_FLAT; }
  else if (tile < T_VH  ){ src=p.vr_wego; K=64;  N=32;  ntc=2; t0=T_VEGO; }
  else if (tile < T_ZW1 ){ src=p.vr_wh;   K=64;  N=32;  ntc=2; t0=T_VH; }
  else if (tile < T_ZW2 ){ src=p.z_w1;    K=ZDIM;N=128; ntc=8; t0=T_ZW1; }
  else                   { src=p.z_w2;    K=128; N=128; ntc=8; t0=T_ZW2; }
  int tl = tile - t0, ktI = tl/ntc, ntI = tl%ntc;
  int k = ktI*32 + ((lane>>4)<<3) + j, n = ntI*16 + (lane&15);
  float v = (k<K && n<N) ? src[k*N+n] : 0.f;
  ws[idx] = f2bf(v);
}

#define WV 8
__global__ __launch_bounds__(512) void k_token(P p, float* __restrict__ outp,
                                               const short* __restrict__ wsb) {
  __shared__ __align__(16) float pool[WV*PW];
  __shared__ int mkA[WV][5];
  __shared__ int mksA[WV][5];
  const s16x8* wsv = (const s16x8*)wsb;
  int wid = threadIdx.x >> 6, l = threadIdx.x & 63;
  float* W   = pool + wid*PW;
  short* egoh = (short*)(W + OF_EGO);     // bf16 gelu'd ego_e [64]
  float* tv  = W + OF_TV;
  float* yb  = W + OF_YB;                 // f32 view (ap raw scores)
  short* ybh = (short*)(W + OF_YB);       // bf16 view (LN1/LN2/attn-y)
  float* U   = W + OF_U;
  float* at  = W + OF_AT;
  short* ath = (short*)(W + OF_AT);       // vr-LN bf16 (tail reuse)
  short* zbh = (short*)(W + OF_ZB);       // z vector, bf16 [352]
  float* qeb = W + OF_QEB;
  short* eghh = (short*)(W + OF_EGH);     // bf16 vr ego hidden [32]
  float* ru  = W + OF_RU;
  float* sm  = W + OF_SM;
  float* scs = sm+0; float* wts = sm+5; float* alp = sm+10; float* lg = sm+16;
  float* a2 = sm+26; float* aps = sm+36;
  int* mk  = mkA[wid];
  int* mks = mksA[wid];
  // U overlays
  float* xb = U;                 // phase A input
  float* S  = U + 200;           // phase A raw ego/pair/ter [160]
  float* qb = U;  float* kb = U+180;  float* vb = U+360;   // phase B
  float* hb = U;                                            // phase C (f32 raw)
  short* hbh = (short*)(U + 344);                            // phase C (bf16 gelu'd)
  float* vq = U;                 // tail: vh raw output
  long tok = (long)blockIdx.x*WV + wid;
  int m = l & 15, q = l >> 4;
  int mm = m < 5 ? m : 4;
  int g4 = (wid>>2)<<2;          // z-phase group base (0 or 4)
  int w4 = wid & 3;              // wave index within z-group
#define BFR(tile) wsv[(tile)*64 + l]

  // x load: 198 f32 = 99 float2
  {
    const float2* xr2 = (const float2*)(p.x + (size_t)tok*DX);
    float2* xb2 = (float2*)xb;
    for (int i=l;i<99;i+=64) xb2[i] = xr2[i];
  }
  WF();

  // mask from r = nbr[...,0:3]
  if (l < SLOTS) { int nb = EGO_DD + l*PER;
    mk[l] = (fabsf(xb[nb])>1e-6f || fabsf(xb[nb+1])>1e-6f || fabsf(xb[nb+2])>1e-6f) ? 1 : 0; }
  // save r/u for final z-tail (xb will be overwritten)
  if (l < 30){ int sl=l/6, d=l%6; ru[l] = xb[EGO_DD + sl*PER + d]; }
  WF();
  int nmask = mk[0]+mk[1]+mk[2]+mk[3]+mk[4];
  bool hasany = nmask>0;
  if (l < SLOTS) mks[l] = hasany ? mk[l] : (l==0 ? 1 : 0);

  // ---- ego/pair/ter (M=1) raw+bias -> S[0:160]
  {
    s16x8 aE = packrow(&xb[q*8]);
    s16x8 aP = packrowb(&xb[107], q*8, 10);
    f32x4 e0={0,0,0,0},e1={0,0,0,0},e2={0,0,0,0},e3={0,0,0,0};
    e0=MFMA(aE,BFR(T_EGO+0),e0); e1=MFMA(aE,BFR(T_EGO+1),e1);
    e2=MFMA(aE,BFR(T_EGO+2),e2); e3=MFMA(aE,BFR(T_EGO+3),e3);
    f32x4 p0={0,0,0,0},p1={0,0,0,0};
    p0=MFMA(aP,BFR(T_PAIR+0),p0); p1=MFMA(aP,BFR(T_PAIR+1),p1);
    if (l<16){
      S[l]    = e0[0]+p.b_ego[l];    S[16+l] = e1[0]+p.b_ego[16+l];
      S[32+l] = e2[0]+p.b_ego[32+l]; S[48+l] = e3[0]+p.b_ego[48+l];
      S[64+l] = p0[0]+p.b_pair[l];   S[80+l] = p1[0]+p.b_pair[16+l];
    }
  }
  {
    f32x4 t0={0,0,0,0},t1={0,0,0,0},t2={0,0,0,0},t3={0,0,0,0};
    for(int kt=0;kt<3;kt++){
      s16x8 aT = packrowb(&xb[117], kt*32+q*8, 81);
      t0=MFMA(aT,BFR(T_TER+kt*4+0),t0); t1=MFMA(aT,BFR(T_TER+kt*4+1),t1);
      t2=MFMA(aT,BFR(T_TER+kt*4+2),t2); t3=MFMA(aT,BFR(T_TER+kt*4+3),t3);
    }
    if (l<16){
      S[96+l] = t0[0]+p.b_ter[l];    S[112+l]= t1[0]+p.b_ter[16+l];
      S[128+l]= t2[0]+p.b_ter[32+l]; S[144+l]= t3[0]+p.b_ter[48+l];
    }
  }
  // ---- invtok (M=16/5) raw+bias -> tv
  {
    int nb = EGO_DD + mm*PER;
    float a0=xb[nb+6],a1=xb[nb+7],a2v=xb[nb+8];
    float nrm = sqrtf(a0*a0+a1*a1+a2v*a2v);
    s16x8 af;
    #pragma unroll
    for(int j=0;j<8;j++){
      int k=q*8+j; float v;
      if(k<6) v=xb[nb+9+k];
      else if(k<9) v=xb[nb+k];
      else if(k==9) v=nrm;
      else v=0.f;
      af[j]=f2bf(v);
    }
    f32x4 c0={0,0,0,0},c1={0,0,0,0};
    c0=MFMA(af,BFR(T_INV+0),c0); c1=MFMA(af,BFR(T_INV+1),c1);
    #pragma unroll
    for(int r=0;r<4;r++){ int row=q*4+r;
      if(row<SLOTS){
        tv[row*ST+m]    = c0[r]+p.b_invtok[m];
        tv[row*ST+16+m] = c1[r]+p.b_invtok[16+m];
      }
    }
  }
  WF();
  // gelu(S) -> zbh[0:160] bf16 (+ egoh copy of first 64)
  if (l<40){
    f32x4 v = *(f32x4*)&S[l*4];
    s16x4 o;
    #pragma unroll
    for(int j=0;j<4;j++) o[j]=f2bf(gelu_f(v[j]));
    *(s16x4*)&zbh[l*4]=o;
    if (l<16) *(s16x4*)&egoh[l*4]=o;
  }
  // tv gelu (vec4, masked)
  if (l<40){
    int sl=l>>3, i4=(l&7)*4;
    f32x4 v = *(f32x4*)&tv[sl*ST+i4];
    if (mk[sl]){
      #pragma unroll
      for(int j=0;j<4;j++) v[j]=gelu_f(v[j]);
    } else { v = (f32x4){0.f,0.f,0.f,0.f}; }
    *(f32x4*)&tv[sl*ST+i4]=v;
  }
  WF();   // xb/S dead from here; U becomes qb/kb/vb

  // ---- LN1 -> bf16 ybh -> qkv
  ln5x32h(tv, ybh, p.ln1_s, p.ln1_b, l);
  WF();
  {
    s16x8 aY = *(const s16x8*)&ybh[mm*YHS + q*8];
    f32x4 q0={0,0,0,0},q1={0,0,0,0},k0v={0,0,0,0},k1v={0,0,0,0},v0={0,0,0,0},v1={0,0,0,0};
    q0=MFMA(aY,BFR(T_Q+0),q0);   q1=MFMA(aY,BFR(T_Q+1),q1);
    k0v=MFMA(aY,BFR(T_K+0),k0v); k1v=MFMA(aY,BFR(T_K+1),k1v);
    v0=MFMA(aY,BFR(T_V+0),v0);   v1=MFMA(aY,BFR(T_V+1),v1);
    #pragma unroll
    for(int r=0;r<4;r++){ int row=q*4+r;
      if(row<SLOTS){
        qb[row*ST+m]=q0[r]+p.bq[m];     qb[row*ST+16+m]=q1[r]+p.bq[16+m];
        kb[row*ST+m]=k0v[r]+p.bk[m];    kb[row*ST+16+m]=k1v[r]+p.bk[16+m];
        vb[row*ST+m]=v0[r]+p.bv[m];     vb[row*ST+16+m]=v1[r]+p.bv[16+m];
      }
    }
  }
  WF();
  // attention scores
  for (int t=l; t<100; t+=64){
    int h=t/25, r2=t%25, qs=r2/5, ks=r2%5;
    const f32x4* qp=(const f32x4*)&qb[qs*ST+h*8];
    const f32x4* kp=(const f32x4*)&kb[ks*ST+h*8];
    f32x4 q0=qp[0], q1=qp[1], k0=kp[0], k1=kp[1];
    float d8 = q0[0]*k0[0]+q0[1]*k0[1]+q0[2]*k0[2]+q0[3]*k0[3]
             + q1[0]*k1[0]+q1[1]*k1[1]+q1[2]*k1[2]+q1[3]*k1[3];
    at[t] = (mks[qs]&&mks[ks]) ? d8*0.35355339059327373f : NEGB;
  }
  WF();
  // softmax over ks (20 lanes)
  if (l<20){
    float e[5]; float mx=NEGB, se=0.f;
    #pragma unroll
    for(int ks=0;ks<5;ks++) mx=fmaxf(mx, at[l*5+ks]);
    #pragma unroll
    for(int ks=0;ks<5;ks++){ e[ks]=__expf(at[l*5+ks]-mx); se+=e[ks]; }
    float inv=1.f/se;
    #pragma unroll
    for(int ks=0;ks<5;ks++) at[l*5+ks]=e[ks]*inv;
  }
  WF();
  // attn @ v -> ybh bf16
  if (l<40){
    int sl=l>>3, i4=(l&7)*4, h=i4>>3, d=i4&7;
    f32x4 acc={0.f,0.f,0.f,0.f};
    #pragma unroll
    for(int ks=0;ks<5;ks++){
      float w = at[(h*5+sl)*5+ks];
      f32x4 vv = *(const f32x4*)&vb[ks*ST+h*8+d];
      acc += vv*w;
    }
    s16x4 o;
    #pragma unroll
    for(int j=0;j<4;j++) o[j]=f2bf(acc[j]);
    *(s16x4*)&ybh[sl*YHS+i4]=o;
  }
  WF();
  // wo + residual (zero_masked)
  {
    s16x8 aY = *(const s16x8*)&ybh[mm*YHS + q*8];
    f32x4 c0={0,0,0,0},c1={0,0,0,0};
    c0=MFMA(aY,BFR(T_O+0),c0); c1=MFMA(aY,BFR(T_O+1),c1);
    #pragma unroll
    for(int r=0;r<4;r++){ int row=q*4+r;
      if(row<SLOTS && mk[row]){
        tv[row*ST+m]    += c0[r]+p.bo[m];
        tv[row*ST+16+m] += c1[r]+p.bo[16+m];
      }
    }
  }
  WF();
  // LN2 + FFN (qb/kb/vb dead; U becomes hb/hbh)
  ln5x32h(tv, ybh, p.ln2_s, p.ln2_b, l);
  WF();
  {
    s16x8 aY = *(const s16x8*)&ybh[mm*YHS + q*8];
    f32x4 c0={0,0,0,0},c1={0,0,0,0},c2={0,0,0,0},c3={0,0,0,0};
    c0=MFMA(aY,BFR(T_W1+0),c0); c1=MFMA(aY,BFR(T_W1+1),c1);
    c2=MFMA(aY,BFR(T_W1+2),c2); c3=MFMA(aY,BFR(T_W1+3),c3);
    #pragma unroll
    for(int r=0;r<4;r++){ int row=q*4+r;
      if(row<SLOTS){
        hb[row*HBST+m]   =c0[r]+p.b1[m];
        hb[row*HBST+16+m]=c1[r]+p.b1[16+m];
        hb[row*HBST+32+m]=c2[r]+p.b1[32+m];
        hb[row*HBST+48+m]=c3[r]+p.b1[48+m];
      }
    }
  }
  WF();
  for (int t=l;t<80;t+=64){
    int sl=t>>4, j4=(t&15)*4;
    f32x4 v = *(f32x4*)&hb[sl*HBST+j4];
    s16x4 o;
    #pragma unroll
    for(int j=0;j<4;j++) o[j]=f2bf(gelu_f(v[j]));
    *(s16x4*)&hbh[sl*HHS+j4]=o;
  }
  WF();
  {
    f32x4 c0={0,0,0,0},c1={0,0,0,0};
    for(int kt=0;kt<2;kt++){
      s16x8 aH = *(const s16x8*)&hbh[mm*HHS + kt*32 + q*8];
      c0=MFMA(aH,BFR(T_W2+kt*2+0),c0); c1=MFMA(aH,BFR(T_W2+kt*2+1),c1);
    }
    #pragma unroll
    for(int r=0;r<4;r++){ int row=q*4+r;
      if(row<SLOTS){
        float n0 = mk[row] ? tv[row*ST+m]+c0[r]+p.b2[m] : 0.f;
        float n1 = mk[row] ? tv[row*ST+16+m]+c1[r]+p.b2[16+m] : 0.f;
        tv[row*ST+m]=n0; tv[row*ST+16+m]=n1;
      }
    }
  }
  WF();   // tv final

  // pools: mean / max -> zbh bf16
  if (l<32){
    float v0=tv[l],v1=tv[ST+l],v2=tv[2*ST+l],v3=tv[3*ST+l],v4=tv[4*ST+l];
    int cnt = nmask>0?nmask:1;
    zbh[160+l]=f2bf((v0+v1+v2+v3+v4)/(float)cnt);
    float mx=-1e9f;
    if(mk[0])mx=fmaxf(mx,v0); if(mk[1])mx=fmaxf(mx,v1); if(mk[2])mx=fmaxf(mx,v2);
    if(mk[3])mx=fmaxf(mx,v3); if(mk[4])mx=fmaxf(mx,v4);
    zbh[192+l]= f2bf(hasany ? mx : 0.f);
  }
  // fused sp+vr LN: vr-LN -> ath bf16; sp scores -> scs
  ln5_spvr(tv, ath, scs, p.sp_ln_s, p.sp_ln_b, p.vr_ln_s, p.vr_ln_b,
           p.sp_w, p.sp_b[0], l);
  WF();
  // sp softmax (8-lane parallel)
  if (l<8){
    float temp = log1pf(expf(p.sp_lt[0])) + 0.001f;
    bool keep=(l<5)&&(mk[l]!=0);
    float x= keep? temp*scs[l] : NEGB;
    float mx=x;
    mx=fmaxf(mx,__shfl_xor(mx,1,8)); mx=fmaxf(mx,__shfl_xor(mx,2,8)); mx=fmaxf(mx,__shfl_xor(mx,4,8));
    float e= keep? __expf(x-mx):0.f;
    float se=e;
    se+=__shfl_xor(se,1,8); se+=__shfl_xor(se,2,8); se+=__shfl_xor(se,4,8);
    if (l<5) wts[l]= se>0.f? e/se:0.f;
  }
  WF();
  // sp wsum -> zbh
  if (l<32){ float a=0;
    for(int sl=0;sl<5;sl++) a += wts[sl]*tv[sl*ST+l];
    zbh[224+l]=f2bf(a); }
  // ap_wq (M=1, K=64) from egoh -> qeb
  {
    f32x4 c0={0,0,0,0},c1={0,0,0,0};
    for(int kt=0;kt<2;kt++){
      s16x8 aE = *(const s16x8*)&egoh[kt*32 + q*8];
      c0=MFMA(aE,BFR(T_APQ+kt*2+0),c0); c1=MFMA(aE,BFR(T_APQ+kt*2+1),c1);
    }
    if(l<16){ qeb[l]=c0[0]+p.ap_bq[l]; qeb[16+l]=c1[0]+p.ap_bq[16+l]; }
  }
  WF();
  // ap_wk + qeb -> yb (raw, pre-tanh)
  {
    s16x8 aT = packrow(&tv[mm*ST + q*8]);
    f32x4 c0={0,0,0,0},c1={0,0,0,0};
    c0=MFMA(aT,BFR(T_APK+0),c0); c1=MFMA(aT,BFR(T_APK+1),c1);
    #pragma unroll
    for(int r=0;r<4;r++){ int row=q*4+r;
      if(row<SLOTS){
        yb[row*ST+m]   =c0[r]+p.ap_bk[m]+qeb[m];
        yb[row*ST+16+m]=c1[r]+p.ap_bk[16+m]+qeb[16+m];
      }
    }
  }
  WF();
  // ap score: tanh fused into the reduce
  for (int sp=0; sp<6; sp+=2){
    int sl = sp + (l>>5), i = l&31;
    float v = (sl<SLOTS) ? tanh_f(yb[sl*ST+i])*p.ap_we[i] : 0.f;
    v=red5(v);
    if (sl<SLOTS && i==0) aps[sl]=v+p.ap_be[0];
  }
  WF();
  // ap softmax (8-lane parallel)
  if (l<8){
    bool keep=(l<5)&&(mk[l]!=0);
    float x= keep? aps[l] : NEGB;
    float mx=x;
    mx=fmaxf(mx,__shfl_xor(mx,1,8)); mx=fmaxf(mx,__shfl_xor(mx,2,8)); mx=fmaxf(mx,__shfl_xor(mx,4,8));
    float e= keep? __expf(x-mx):0.f;
    float se=e;
    se+=__shfl_xor(se,1,8); se+=__shfl_xor(se,2,8); se+=__shfl_xor(se,4,8);
    if (l<5) alp[l]= se>0.f? e/se:0.f;
  }
  WF();
  // ap wsum -> zbh; flat (gelu fused in epilogue); vego -> eghh bf16
  if (l<32){ float a=0;
    for(int sl=0;sl<5;sl++) a += alp[sl]*tv[sl*ST+l];
    zbh[256+l]=f2bf(a); }
  {
    f32x4 c0={0,0,0,0},c1={0,0,0,0};
    for(int kt=0;kt<5;kt++){
      s16x8 aF = packrow(&tv[kt*ST + q*8]);
      c0=MFMA(aF,BFR(T_FLAT+kt*2+0),c0); c1=MFMA(aF,BFR(T_FLAT+kt*2+1),c1);
    }
    if(l<16){
      zbh[288+l]=f2bf(0.25f*gelu_f(c0[0]+p.flat_b[l]));
      zbh[304+l]=f2bf(0.25f*gelu_f(c1[0]+p.flat_b[16+l]));
    }
  }
  {
    f32x4 c0={0,0,0,0},c1={0,0,0,0};
    for(int kt=0;kt<2;kt++){
      s16x8 aE = *(const s16x8*)&egoh[kt*32 + q*8];
      c0=MFMA(aE,BFR(T_VEGO+kt*2+0),c0); c1=MFMA(aE,BFR(T_VEGO+kt*2+1),c1);
    }
    if(l<16){ eghh[l]=f2bf(c0[0]+p.vr_bego[l]); eghh[16+l]=f2bf(c1[0]+p.vr_bego[16+l]); }
  }
  WF();
  // vh MFMA (ath | eghh) -> vq raw
  {
    s16x8 aY = *(const s16x8*)&ath[mm*YHS + q*8];
    s16x8 aE = *(const s16x8*)&eghh[q*8];
    f32x4 c0={0,0,0,0},c1={0,0,0,0};
    c0=MFMA(aY,BFR(T_VH+0),c0); c1=MFMA(aY,BFR(T_VH+1),c1);
    c0=MFMA(aE,BFR(T_VH+2),c0); c1=MFMA(aE,BFR(T_VH+3),c1);
    #pragma unroll
    for(int r=0;r<4;r++){ int row=q*4+r;
      if(row<SLOTS){
        vq[row*ST+m]   =c0[r]+p.vr_bh[m];
        vq[row*ST+16+m]=c1[r]+p.vr_bh[16+m];
      }
    }
  }
  WF();
  // vr logits: gelu fused, dual-reduce, 3 passes
  for (int sp=0; sp<6; sp+=2){
    int sl = sp + (l>>5), i = l&31;
    bool act = sl < SLOTS;
    float g = act ? gelu_f(vq[sl*ST+i]) : 0.f;
    float v0 = g*p.vr_wl[i*2], v1 = g*p.vr_wl[i*2+1];
    red5_2(v0,v1);
    if(act && i==0){ lg[sl*2]=v0+p.vr_bl[0]; lg[sl*2+1]=v1+p.vr_bl[1]; }
  }
  WF();
  // vr softmax (2 rows, 8-lane groups)
  if (l<16){
    int s=l&7, hh=l>>3;
    bool keep=(s<5)&&(mk[s<5?s:0]!=0);
    float x= keep? lg[(s<5?s:0)*2+hh] : NEGB;
    float mx=x;
    mx=fmaxf(mx,__shfl_xor(mx,1,8)); mx=fmaxf(mx,__shfl_xor(mx,2,8)); mx=fmaxf(mx,__shfl_xor(mx,4,8));
    float e= keep? __expf(x-mx):0.f;
    float se=e;
    se+=__shfl_xor(se,1,8); se+=__shfl_xor(se,2,8); se+=__shfl_xor(se,4,8);
    if (s<5) a2[s*2+hh]= se>0.f? e/se:0.f;
  }
  WF();
  // v_r / v_u tail -> zbh; zero pad 332..351
  if (l<12){ int w = l/6, rem=l%6, hh=rem/3, d=rem%3;
    float a=0;
    for(int sl=0;sl<5;sl++) a += a2[sl*2+hh]*ru[sl*6 + w*3 + d];
    zbh[320 + w*6 + hh*3 + d]=f2bf(a); }
  else if (l<32) zbh[320+l]=0;
  __syncthreads();   // cross-wave: z-group tokens' zbh needed below

  // ---- fused z-phase (MFMA): GEMM1 K=352, two independent 4-wave groups
  {
    f32x4 acc0 = {0.f,0.f,0.f,0.f}, acc1 = {0.f,0.f,0.f,0.f};
    const short* zbhM = (const short*)(pool + (g4 + (m<4?m:0))*PW + OF_ZB);
    for (int kt=0; kt<11; kt++){
      s16x8 af;
      if (m < 4) af = *(const s16x8*)&zbhM[kt*32 + q*8];
      else {
        #pragma unroll
        for (int j=0;j<8;j++) af[j]=0;
      }
      s16x8 b0 = wsv[(T_ZW1 + kt*8 + 2*w4  )*64 + l];
      s16x8 b1 = wsv[(T_ZW1 + kt*8 + 2*w4+1)*64 + l];
      acc0 = MFMA(af, b0, acc0);
      acc1 = MFMA(af, b1, acc1);
    }
    if (q == 0){
      int c0 = 2*w4*16 + m, c1 = (2*w4+1)*16 + m;
      float bb0 = p.z_b1[c0], bb1 = p.z_b1[c1];
      #pragma unroll
      for (int r=0;r<4;r++){
        pool[(g4+r)*PW + OF_U + c0] = gelu_f(acc0[r] + bb0);   // h1
        pool[(g4+r)*PW + OF_U + c1] = gelu_f(acc1[r] + bb1);
      }
    }
  }
  __syncthreads();
  // LN1 on own token's h1 -> h1h (bf16), dual-tree
  {
    float v0 = pool[wid*PW + OF_U + l], v1 = pool[wid*PW + OF_U + l+64];
    float sum = v0+v1, qq = v0*v0+v1*v1;
    for (int o=32;o>=1;o>>=1){ sum += __shfl_xor(sum,o,64); qq += __shfl_xor(qq,o,64); }
    float mu = sum*(1.f/128.f);
    float rs = rsqrtf(qq*(1.f/128.f)-mu*mu+1e-6f);
    short* h1h = (short*)(W + OF_U + 476);
    h1h[l]    = f2bf((v0-mu)*rs*p.z_ln1_s[l]   +p.z_ln1_b[l]);
    h1h[l+64] = f2bf((v1-mu)*rs*p.z_ln1_s[l+64]+p.z_ln1_b[l+64]);
  }
  __syncthreads();
  // GEMM2 K=128
  {
    f32x4 acc0 = {0.f,0.f,0.f,0.f}, acc1 = {0.f,0.f,0.f,0.f};
    const short* h1hM = (const short*)(pool + (g4 + (m<4?m:0))*PW + OF_U + 476);
    for (int kt=0; kt<4; kt++){
      s16x8 af;
      if (m < 4) af = *(const s16x8*)&h1hM[kt*32 + q*8];
      else {
        #pragma unroll
        for (int j=0;j<8;j++) af[j]=0;
      }
      s16x8 b0 = wsv[(T_ZW2 + kt*8 + 2*w4  )*64 + l];
      s16x8 b1 = wsv[(T_ZW2 + kt*8 + 2*w4+1)*64 + l];
      acc0 = MFMA(af, b0, acc0);
      acc1 = MFMA(af, b1, acc1);
    }
    if (q == 0){
      int c0 = 2*w4*16 + m, c1 = (2*w4+1)*16 + m;
      float bb0 = p.z_b2[c0], bb1 = p.z_b2[c1];
      #pragma unroll
      for (int r=0;r<4;r++){
        pool[(g4+r)*PW + OF_U + 128 + c0] = gelu_f(acc0[r] + bb0);   // h2
        pool[(g4+r)*PW + OF_U + 128 + c1] = gelu_f(acc1[r] + bb1);
      }
    }
  }
  __syncthreads();
  // LN2 per wave + store (dual-tree)
  {
    float v0 = pool[wid*PW + OF_U + 128 + l], v1 = pool[wid*PW + OF_U + 128 + l+64];
    float sum = v0+v1, qq = v0*v0+v1*v1;
    for (int o=32;o>=1;o>>=1){ sum += __shfl_xor(sum,o,64); qq += __shfl_xor(qq,o,64); }
    float mu = sum*(1.f/128.f);
    float rs = rsqrtf(qq*(1.f/128.f)-mu*mu+1e-6f);
    float o0 = (v0-mu)*rs*p.z_ln2_s[l]   +p.z_ln2_b[l];
    float o1 = (v1-mu)*rs*p.z_ln2_s[l+64]+p.z_ln2_b[l+64];
    float* op = outp + (size_t)tok*128;
    op[l]    = o0;
    op[l+64] = o1;
  }
}

extern "C" void kernel_launch(void* const* d_in, const int* in_sizes, int n_in,
                              void* d_out, int out_size, void* d_ws, size_t ws_size,
                              hipStream_t stream) {
  (void)in_sizes; (void)n_in; (void)out_size; (void)ws_size;
  P p;
  const void** pp = (const void**)&p;
  for (int i=0;i<54;i++) pp[i] = d_in[i];
  short* wsb = (short*)d_ws;   // 184320 B needed
  k_prep<<<(T_TOT*512+255)/256, 256, 0, stream>>>(p, wsb);
  k_token<<<NTOK/WV, 512, 0, stream>>>(p, (float*)d_out, wsb);
}